// Round 18
// baseline (351.441 us; speedup 1.0000x reference)
//
#include <hip/hip_runtime.h>
#include <hip/hip_bf16.h>
#include <cstdint>
#include <cstddef>

#define DD   1024
#define DD2  2048
#define EE   8
#define NTOK 4096   // B*S
#define CAPR 10240  // max gathered rows: 2*NTOK + 8*256 alignment pad
#define MAXT1 72    // max active 128-row tiles
#define MAXT2 40    // max active 256-row tiles

typedef __bf16 bf16_t;
typedef __bf16 bf16x8 __attribute__((ext_vector_type(8)));
typedef __bf16 bf16x4 __attribute__((ext_vector_type(4)));
typedef float  f32x4v __attribute__((ext_vector_type(4)));

// tanh-form GELU (~1e-3 max err; slack is 3x)
__device__ __forceinline__ float gelu_f(float v){
  const float t = v*(0.7978845608028654f + 0.0356774081f*v*v);
  const float u = __expf(2.0f*t);
  return __fdividef(v*u, 1.0f + u);
}

__device__ __forceinline__ void gload_lds16(const void* g, void* l){
  __builtin_amdgcn_global_load_lds(
    (const __attribute__((address_space(1))) unsigned int*)(uintptr_t)g,
    (__attribute__((address_space(3))) unsigned int*)(uintptr_t)l,
    16, 0, 0);
}

enum { EPI_GELU_F32=0, EPI_GELU_BF16=1, EPI_BIAS_BF16=2, EPI_SCALE_BF16=3,
       EPI_ADDV_BF16=4, EPI_BF16=5, EPI_F32=6 };

// ---------- 4-wave kernel (down / abel / PS chain / rot) ----------
// C = al*(A @ Bt^T) [+epi]. 3-deep, BK=32, counted vmcnt + raw s_barrier.
template<int BM,int BN,int EPI,bool TAB>
__global__ __launch_bounds__(256)
void gemm_bt(const bf16_t* __restrict__ A, const bf16_t* __restrict__ Bt,
             const int N, const int K, const int gx, const int gy, const int gz,
             const long sAz, const long sBz, const long sOz,
             const int* __restrict__ tileE, const int* __restrict__ tileR,
             const int* __restrict__ ntp, const int* __restrict__ offp,
             const int* __restrict__ tokOf,
             const float* __restrict__ bias, const long sBias,
             const float alpha,
             const bf16_t* __restrict__ addv,
             float* __restrict__ outF, bf16_t* __restrict__ outB)
{
  constexpr int BK = 32;
  constexpr int WM = BM/2, WN = BN/2;
  constexpr int FM = WM/16, FN = WN/16;
  constexpr int IA = BM/64, IB = BN/64;
  constexpr int NLD = IA + IB;
  __shared__ alignas(16) bf16_t sA[3][BM*BK];
  __shared__ alignas(16) bf16_t sB[3][BN*BK];

  int bx, by, bz; long ro = 0;
  if constexpr (TAB) {
    const int nwg = gx * gy;
    const int q = nwg >> 3, r = nwg & 7;
    const int k = blockIdx.x & 7, i = blockIdx.x >> 3;
    if (i >= q + (k < r ? 1 : 0)) return;
    const int l = k * q + (k < r ? k : r) + i;
    const int ti = l / gx; bx = l - ti*gx;
    if (ti >= ntp[0]) return;
    bz = tileE[ti]; by = 0;
    ro = (long)offp[bz] + tileR[ti];
  } else {
    const int nwg = gx * gy * gz;
    const int q = nwg >> 3, r = nwg & 7;
    const int k = blockIdx.x & 7, i = blockIdx.x >> 3;
    if (i >= q + (k < r ? 1 : 0)) return;
    const int l = k * q + (k < r ? k : r) + i;
    bx = l % gx; const int t2 = l / gx; by = t2 % gy; bz = t2 / gy;
  }

  const int z = bz;
  const bf16_t* Bp = Bt + (size_t)z * sBz;
  float*  oF = outF;
  bf16_t* oB = outB;
  if constexpr (TAB) {
    oB += ro * (long)N;
  } else {
    A += (size_t)z * sAz;
    if (oF) oF += (size_t)z * sOz;
    if (oB) oB += (size_t)z * sOz;
  }
  const float*  bp = bias ? bias + (size_t)z * sBias : nullptr;
  const bf16_t* vp = addv ? addv + (size_t)z * sOz   : nullptr;

  const int tid = threadIdx.x;
  const int wid = tid >> 6, lid = tid & 63;
  const int wr = wid >> 1, wc = wid & 1;
  const int brow = (TAB ? 0 : by * BM), bcol = bx * BN;
  const int fr = lid & 15, fq = lid >> 4;
  const int rl = lid >> 2, qs = lid & 3;

  const char* aSrc[IA];
  const char* bSrc[IB];
  #pragma unroll
  for (int i = 0; i < IA; i++) {
    const int rloc = (wid*IA + i)*16 + rl;
    const int q = qs ^ ((rloc >> 1) & 3);
    const bf16_t* arow;
    if constexpr (TAB) {
      arow = tokOf ? (A + (size_t)tokOf[ro + rloc] * K)
                   : (A + (size_t)(ro + rloc) * K);
    } else {
      arow = A + (size_t)(brow + rloc) * K;
    }
    aSrc[i] = (const char*)arow + q*16;
  }
  #pragma unroll
  for (int i = 0; i < IB; i++) {
    const int rloc = (wid*IB + i)*16 + rl;
    const int q = qs ^ ((rloc >> 1) & 3);
    bSrc[i] = (const char*)(Bp + (size_t)(bcol + rloc) * K) + q*16;
  }

  f32x4v acc[FM][FN] = {};

  auto stage = [&](int buf, int kt) {
    #pragma unroll
    for (int i = 0; i < IA; i++)
      gload_lds16(aSrc[i] + (size_t)kt*2, (char*)sA[buf] + (wid*IA + i)*1024);
    #pragma unroll
    for (int i = 0; i < IB; i++)
      gload_lds16(bSrc[i] + (size_t)kt*2, (char*)sB[buf] + (wid*IB + i)*1024);
  };

  stage(0, 0);
  stage(1, BK);
  const int nk = K / BK;
  int b0 = 0, b1 = 1, b2 = 2;

  for (int t = 0; t < nk; ++t) {
    if (t < nk - 1) asm volatile("s_waitcnt vmcnt(%0)" :: "i"(NLD) : "memory");
    else            asm volatile("s_waitcnt vmcnt(0)" ::: "memory");
    __builtin_amdgcn_s_barrier();
    __builtin_amdgcn_sched_barrier(0);
    if (t + 2 < nk) stage(b2, (t + 2)*BK);

    bf16x8 af[FM], bb[FN];
    #pragma unroll
    for (int mi = 0; mi < FM; mi++) {
      const int r2 = wr*WM + mi*16 + fr;
      const int q = fq ^ ((r2 >> 1) & 3);
      af[mi] = *(const bf16x8*)((const char*)sA[b0] + r2*64 + q*16);
    }
    #pragma unroll
    for (int ni = 0; ni < FN; ni++) {
      const int r2 = wc*WN + ni*16 + fr;
      const int q = fq ^ ((r2 >> 1) & 3);
      bb[ni] = *(const bf16x8*)((const char*)sB[b0] + r2*64 + q*16);
    }
    #pragma unroll
    for (int mi = 0; mi < FM; mi++)
      #pragma unroll
      for (int ni = 0; ni < FN; ni++)
        acc[mi][ni] = __builtin_amdgcn_mfma_f32_16x16x32_bf16(
            af[mi], bb[ni], acc[mi][ni], 0, 0, 0);

    const int tb_ = b0; b0 = b1; b1 = b2; b2 = tb_;
  }

  #pragma unroll
  for (int mi = 0; mi < FM; mi++) {
    #pragma unroll
    for (int ni = 0; ni < FN; ni++) {
      const int rg0 = brow + wr*WM + mi*16 + fq*4;
      const int cg  = bcol + wc*WN + ni*16 + fr;
      #pragma unroll
      for (int i = 0; i < 4; i++) {
        const int rg = rg0 + i;
        float v = acc[mi][ni][i];
        if constexpr (EPI == EPI_GELU_F32) {
          v += bp[cg];
          oF[(size_t)rg*N + cg] = gelu_f(v);
        } else if constexpr (EPI == EPI_GELU_BF16) {
          v += bp[cg];
          oB[(size_t)rg*N + cg] = (bf16_t)gelu_f(v);
        } else if constexpr (EPI == EPI_BIAS_BF16) {
          v += bp[cg];
          oB[(size_t)rg*N + cg] = (bf16_t)v;
        } else if constexpr (EPI == EPI_SCALE_BF16) {
          oB[(size_t)rg*N + cg] = (bf16_t)(v * alpha);
        } else if constexpr (EPI == EPI_ADDV_BF16) {
          oB[(size_t)rg*N + cg] = (bf16_t)(v + (float)vp[(size_t)rg*N + cg]);
        } else if constexpr (EPI == EPI_BF16) {
          oB[(size_t)rg*N + cg] = (bf16_t)v;
        } else {
          oF[(size_t)rg*N + cg] = v;
        }
      }
    }
  }
}

// ---------- 8-wave 256x256 up-proj: 4-deep counted-vmcnt + setprio ----------
// BK=32, 4 LDS buffers (128 KB), 32 MFMA + 8 ds_read per barrier, vmcnt(8)
// steady-state (2 stages in flight). stage(t+3) after barrier(t) targets
// buf (t-1)&3 whose readers all crossed barrier(t) -> race-free. vmcnt(8)
// leaves stages t+1,t+2 in flight -> buf t&3 landed. Same swizzle/layout as
// the 4-wave kernel (64B rows, quad = q0 ^ ((row>>1)&3)).
__global__ __launch_bounds__(512)
void gemm_up8(const bf16_t* __restrict__ A, const bf16_t* __restrict__ Bt,
              const int N, const int K, const int gx,
              const long sBz,
              const int* __restrict__ tileE, const int* __restrict__ tileR,
              const int* __restrict__ ntp, const int* __restrict__ offp,
              const int* __restrict__ tokOf,
              const float* __restrict__ bias, const long sBias,
              bf16_t* __restrict__ outB)
{
  constexpr int BK = 32;
  constexpr int FM = 8, FN = 4;   // wave tile 128x64, waves 2x4
  __shared__ alignas(16) bf16_t sA[4][256*BK];
  __shared__ alignas(16) bf16_t sB[4][256*BK];

  const int nwg = gx * MAXT2;
  const int q0 = nwg >> 3, r0_ = nwg & 7;
  const int kx = blockIdx.x & 7, ii = blockIdx.x >> 3;
  if (ii >= q0 + (kx < r0_ ? 1 : 0)) return;
  const int l0 = kx * q0 + (kx < r0_ ? kx : r0_) + ii;
  const int ti = l0 / gx; const int bx = l0 - ti*gx;
  if (ti >= ntp[0]) return;
  const int e = tileE[ti];
  const long ro = (long)offp[e] + tileR[ti];

  const bf16_t* Bp = Bt + (size_t)e * sBz;
  const float*  bp = bias + (size_t)e * sBias;
  bf16_t* oB = outB + ro * (long)N;

  const int tid = threadIdx.x;
  const int wid = tid >> 6, lid = tid & 63;
  const int wr = wid >> 2, wc = wid & 3;
  const int bcol = bx * 256;
  const int fr = lid & 15, fq = lid >> 4;
  const int srl = lid >> 2, sq = lid & 3;

  // per-lane pre-swizzled sources; load i covers rows [i*128, i*128+128)
  const char* aSrc[2]; const char* bSrc[2];
  #pragma unroll
  for (int i = 0; i < 2; i++) {
    const int rloc = i*128 + wid*16 + srl;
    const int qa = sq ^ ((rloc >> 1) & 3);
    aSrc[i] = (const char*)(A + (size_t)tokOf[ro + rloc] * K) + qa*16;
    const int qb = sq ^ ((rloc >> 1) & 3);
    bSrc[i] = (const char*)(Bp + (size_t)(bcol + rloc) * K) + qb*16;
  }

  f32x4v acc[FM][FN] = {};

  auto stage = [&](int buf, int kt) {
    #pragma unroll
    for (int i = 0; i < 2; i++)
      gload_lds16(aSrc[i] + (size_t)kt*2, (char*)sA[buf] + i*8192 + wid*1024);
    #pragma unroll
    for (int i = 0; i < 2; i++)
      gload_lds16(bSrc[i] + (size_t)kt*2, (char*)sB[buf] + i*8192 + wid*1024);
  };

  stage(0, 0);
  stage(1, BK);
  stage(2, 2*BK);
  const int nk = K / BK;

  for (int t = 0; t < nk; ++t) {
    if (t < nk - 2)      asm volatile("s_waitcnt vmcnt(8)" ::: "memory");
    else if (t == nk - 2) asm volatile("s_waitcnt vmcnt(4)" ::: "memory");
    else                 asm volatile("s_waitcnt vmcnt(0)" ::: "memory");
    __builtin_amdgcn_s_barrier();
    __builtin_amdgcn_sched_barrier(0);
    if (t + 3 < nk) stage((t + 3) & 3, (t + 3)*BK);

    const int b = t & 3;
    bf16x8 bb[FN];
    #pragma unroll
    for (int ni = 0; ni < FN; ni++) {
      const int r2 = wc*64 + ni*16 + fr;
      const int q = fq ^ ((r2 >> 1) & 3);
      bb[ni] = *(const bf16x8*)((const char*)sB[b] + r2*64 + q*16);
    }
    __builtin_amdgcn_s_setprio(1);
    #pragma unroll
    for (int mi = 0; mi < FM; mi++) {
      const int r2 = wr*128 + mi*16 + fr;
      const int q = fq ^ ((r2 >> 1) & 3);
      const bf16x8 af = *(const bf16x8*)((const char*)sA[b] + r2*64 + q*16);
      #pragma unroll
      for (int ni = 0; ni < FN; ni++)
        acc[mi][ni] = __builtin_amdgcn_mfma_f32_16x16x32_bf16(
            af, bb[ni], acc[mi][ni], 0, 0, 0);
    }
    __builtin_amdgcn_s_setprio(0);
  }

  #pragma unroll
  for (int mi = 0; mi < FM; mi++) {
    #pragma unroll
    for (int ni = 0; ni < FN; ni++) {
      const int rg0 = wr*128 + mi*16 + fq*4;
      const int cg  = bcol + wc*64 + ni*16 + fr;
      #pragma unroll
      for (int i = 0; i < 4; i++) {
        const float v = acc[mi][ni][i] + bp[cg];
        oB[(size_t)(rg0 + i)*N + cg] = (bf16_t)gelu_f(v);
      }
    }
  }
}

// ---- weight prep (67us-converged family) ----
__device__ __forceinline__ void tcvt_tile(const float* __restrict__ src,
                                          bf16_t* __restrict__ dst,
                                          int R, int C, int bx, int by,
                                          float (*t)[65]){
  const int c0 = bx*64, r0 = by*64;
  const int lx = threadIdx.x & 15, ly = threadIdx.x >> 4;
  #pragma unroll
  for (int i = 0; i < 4; i++) {
    const int row = r0 + ly + i*16;
    const float4 v = *(const float4*)(src + (size_t)row*C + c0 + lx*4);
    t[ly + i*16][lx*4+0] = v.x; t[ly + i*16][lx*4+1] = v.y;
    t[ly + i*16][lx*4+2] = v.z; t[ly + i*16][lx*4+3] = v.w;
  }
  __syncthreads();
  #pragma unroll
  for (int i = 0; i < 4; i++) {
    const int c = c0 + ly + i*16;
    bf16x4 o;
    #pragma unroll
    for (int j = 0; j < 4; j++) o[j] = (bf16_t)t[lx*4+j][ly + i*16];
    *(bf16x4*)(dst + (size_t)c*R + r0 + lx*4) = o;
  }
}

__global__ __launch_bounds__(256)
void prep_kernel(const float* __restrict__ abel_w, bf16_t* __restrict__ abel_wT,
                 const float* __restrict__ ew1, bf16_t* __restrict__ ew1T,
                 const float* __restrict__ ew2, bf16_t* __restrict__ ew2T,
                 const float* __restrict__ gens, bf16_t* __restrict__ Hn)
{
  __shared__ float t[64][65];
  const int bid = blockIdx.x;
  if (bid < 256) {
    tcvt_tile(abel_w, abel_wT, DD, DD, bid & 15, bid >> 4, t);
  } else if (bid < 4352) {
    const int i = bid - 256, z = i >> 9, r = i & 511;
    tcvt_tile(ew1 + (size_t)z*DD*DD2, ew1T + (size_t)z*DD2*DD, DD, DD2, r & 31, r >> 5, t);
  } else if (bid < 8448) {
    const int i = bid - 4352, z = i >> 9, r = i & 511;
    tcvt_tile(ew2 + (size_t)z*DD2*DD, ew2T + (size_t)z*DD*DD2, DD2, DD, r & 15, r >> 4, t);
  } else {
    const long i4 = ((long)(bid - 8448)*256 + threadIdx.x)*4;
    const float4 v = *(const float4*)(gens + i4);
    bf16x4 b; b[0]=(bf16_t)(-v.x); b[1]=(bf16_t)(-v.y);
    b[2]=(bf16_t)(-v.z); b[3]=(bf16_t)(-v.w);
    *(bf16x4*)(Hn + i4) = b;
  }
}

// bf16 [D,D] transpose: Tb[z] = Ut[1-z]^T  (z = 0,1)
__global__ __launch_bounds__(256)
void tb16_kernel(const bf16_t* __restrict__ Ut, bf16_t* __restrict__ Tb){
  __shared__ bf16_t tile[32][33];
  const bf16_t* src = Ut + (size_t)(1 - blockIdx.z) * DD * DD;
  bf16_t*       dst = Tb + (size_t)blockIdx.z * DD * DD;
  const int c0 = blockIdx.x*32, r0 = blockIdx.y*32;
  #pragma unroll
  for (int i = 0; i < 4; i++)
    tile[threadIdx.y + i*8][threadIdx.x] = src[(size_t)(r0 + threadIdx.y + i*8)*DD + c0 + threadIdx.x];
  __syncthreads();
  #pragma unroll
  for (int i = 0; i < 4; i++)
    dst[(size_t)(c0 + threadIdx.y + i*8)*DD + r0 + threadIdx.x] = tile[threadIdx.x][threadIdx.y + i*8];
}

// Degree-5 PS pieces: V = I + H + H2/2 ; Wt = I/6 - H/24 + H2/120
__global__ __launch_bounds__(256)
void vw_kernel(const bf16_t* __restrict__ Hn, const bf16_t* __restrict__ H2,
               bf16_t* __restrict__ Vb, bf16_t* __restrict__ Wtb){
  const long i0 = ((long)blockIdx.x*256 + threadIdx.x)*4;
  const long rc = i0 % (long)(DD*DD);
  const int r = (int)(rc / DD), c0 = (int)(rc % DD);
  const bf16x4 h  = *(const bf16x4*)(Hn + i0);
  const bf16x4 h2 = *(const bf16x4*)(H2 + i0);
  bf16x4 v, w;
  #pragma unroll
  for (int j = 0; j < 4; j++) {
    const float d  = (r == c0 + j) ? 1.0f : 0.0f;
    const float fh = (float)h[j], f2 = (float)h2[j];
    v[j] = (bf16_t)(d + fh + f2*0.5f);
    w[j] = (bf16_t)(d*(1.0f/6.0f) - fh*(1.0f/24.0f) + f2*(1.0f/120.0f));
  }
  *(bf16x4*)(Vb  + i0) = v;
  *(bf16x4*)(Wtb + i0) = w;
}

// LayerNorm -> xnb (bf16); gate logits -> per-token top-2 ids + softmax weights.
__global__ __launch_bounds__(256)
void ln_gate_kernel(const float* __restrict__ x, const float* __restrict__ gamma,
                    const float* __restrict__ beta, const float* __restrict__ gw,
                    const float* __restrict__ gb,
                    bf16_t* __restrict__ xnb, int2* __restrict__ ids,
                    float2* __restrict__ wts)
{
  const int t = blockIdx.x, tid = threadIdx.x, j0 = tid*4;
  const int wid = tid >> 6, lid = tid & 63;
  const float4 v = *(const float4*)(x + (size_t)t*DD + j0);
  float s  = v.x + v.y + v.z + v.w;
  float ss = v.x*v.x + v.y*v.y + v.z*v.z + v.w*v.w;
  #pragma unroll
  for (int off = 32; off; off >>= 1) { s += __shfl_down(s, off); ss += __shfl_down(ss, off); }
  __shared__ float redS[4], redQ[4], mv[2];
  if (lid == 0) { redS[wid] = s; redQ[wid] = ss; }
  __syncthreads();
  if (tid == 0) {
    const float S1 = redS[0]+redS[1]+redS[2]+redS[3];
    const float S2 = redQ[0]+redQ[1]+redQ[2]+redQ[3];
    const float mu  = S1 * (1.0f/DD);
    const float var = S2 * (1.0f/DD) - mu*mu;
    mv[0] = mu; mv[1] = rsqrtf(var + 1e-5f);
  }
  __syncthreads();
  const float mu = mv[0], rstd = mv[1];
  const float4 g = *(const float4*)(gamma + j0);
  const float4 b = *(const float4*)(beta  + j0);
  float xn[4];
  xn[0] = (v.x-mu)*rstd*g.x + b.x;
  xn[1] = (v.y-mu)*rstd*g.y + b.y;
  xn[2] = (v.z-mu)*rstd*g.z + b.z;
  xn[3] = (v.w-mu)*rstd*g.w + b.w;
  bf16x4 ov; ov[0]=(bf16_t)xn[0]; ov[1]=(bf16_t)xn[1]; ov[2]=(bf16_t)xn[2]; ov[3]=(bf16_t)xn[3];
  *(bf16x4*)(xnb + (size_t)t*DD + j0) = ov;

  float p[8] = {0,0,0,0,0,0,0,0};
  #pragma unroll
  for (int i = 0; i < 4; i++) {
    const float4 a0 = *(const float4*)(gw + (size_t)(j0+i)*EE);
    const float4 a1 = *(const float4*)(gw + (size_t)(j0+i)*EE + 4);
    const float xv = xn[i];
    p[0]+=xv*a0.x; p[1]+=xv*a0.y; p[2]+=xv*a0.z; p[3]+=xv*a0.w;
    p[4]+=xv*a1.x; p[5]+=xv*a1.y; p[6]+=xv*a1.z; p[7]+=xv*a1.w;
  }
  #pragma unroll
  for (int off = 32; off; off >>= 1) {
    #pragma unroll
    for (int e = 0; e < 8; e++) p[e] += __shfl_down(p[e], off);
  }
  __shared__ float pr[32];
  if (lid == 0) {
    #pragma unroll
    for (int e = 0; e < 8; e++) pr[wid*8 + e] = p[e];
  }
  __syncthreads();
  if (tid == 0) {
    float l[8];
    #pragma unroll
    for (int e = 0; e < 8; e++) l[e] = pr[e] + pr[8+e] + pr[16+e] + pr[24+e] + gb[e];
    int i1 = 0; float m1 = l[0];
    #pragma unroll
    for (int e = 1; e < 8; e++) if (l[e] > m1) { m1 = l[e]; i1 = e; }
    int i2 = 0; float m2 = -1e30f;
    #pragma unroll
    for (int e = 0; e < 8; e++) if (e != i1 && l[e] > m2) { m2 = l[e]; i2 = e; }
    const float wa = 1.0f/(1.0f + expf(m2 - m1));  // softmax over top-2
    ids[t] = make_int2(i1, i2);
    wts[t] = make_float2(wa, 1.0f - wa);
  }
}

// Slot assignment (ballot-scan), 256-aligned offsets, dual tile tables:
// tE1/tR1 128-grain (down), tE2/tR2 256-grain (up).
__global__ __launch_bounds__(256)
void route_kernel(const int2* __restrict__ ids, int* __restrict__ slotA,
                  int* __restrict__ slotB, int* __restrict__ cnt,
                  int* __restrict__ off, int* __restrict__ tE1,
                  int* __restrict__ tR1, int* __restrict__ tE2,
                  int* __restrict__ tR2, int* __restrict__ ntp)
{
  const int tid = threadIdx.x;
  const int wid = tid >> 6, lid = tid & 63;
  __shared__ int wsum[EE][4];
  __shared__ int base[EE];
  if (tid < EE) base[tid] = 0;
  __syncthreads();
  const unsigned long long lt = (1ull << lid) - 1ull;
  for (int c0 = 0; c0 < NTOK; c0 += 256) {
    const int t = c0 + tid;
    const int2 id = ids[t];
    int pA = 0, pB = 0;
    #pragma unroll
    for (int e = 0; e < EE; e++) {
      const bool fA = (id.x == e), fB = (id.y == e);
      const unsigned long long mA = __ballot(fA);
      const unsigned long long mB = __ballot(fB);
      const int cA = __popcll(mA);
      if (lid == 0) wsum[e][wid] = cA + __popcll(mB);
      if (fA) pA = __popcll(mA & lt);
      if (fB) pB = cA + __popcll(mB & lt);
    }
    __syncthreads();
    int wbA = base[id.x], wbB = base[id.y];
    for (int w = 0; w < wid; w++) { wbA += wsum[id.x][w]; wbB += wsum[id.y][w]; }
    slotA[t] = wbA + pA;
    slotB[t] = wbB + pB;
    __syncthreads();
    if (tid < EE) base[tid] += wsum[tid][0]+wsum[tid][1]+wsum[tid][2]+wsum[tid][3];
    __syncthreads();
  }
  if (tid == 0) {
    int a = 0, n1 = 0, n2 = 0;
    for (int e = 0; e < EE; e++) {
      cnt[e] = base[e]; off[e] = a;
      for (int r2 = 0; r2 < base[e]; r2 += 128) { tE1[n1] = e; tR1[n1] = r2; n1++; }
      for (int r2 = 0; r2 < base[e]; r2 += 256) { tE2[n2] = e; tR2[n2] = r2; n2++; }
      a += (base[e] + 255) & ~255;
    }
    ntp[0] = n1; ntp[1] = n2;
  }
}

// tokOf[gathered_row] = token; block 0 zeroes pad rows (256-aligned).
__global__ __launch_bounds__(256)
void fill_tok_kernel(const int2* __restrict__ ids, const int* __restrict__ slotA,
                     const int* __restrict__ slotB, const int* __restrict__ off,
                     const int* __restrict__ cnt, int* __restrict__ tokOf){
  const int t = blockIdx.x*256 + threadIdx.x;
  const int2 id = ids[t];
  tokOf[off[id.x] + slotA[t]] = t;
  tokOf[off[id.y] + slotB[t]] = t;
  if (blockIdx.x == 0) {
    for (int e = 0; e < EE; e++) {
      const int c = cnt[e], o = off[e], al = (c + 255) & ~255;
      for (int p = c + threadIdx.x; p < al; p += 256) tokOf[o + p] = 0;
    }
  }
}

// Xa[t] = bf16(w1*Yg[loc1] + w2*Yg[loc2])
__global__ __launch_bounds__(256)
void combine_kernel(const bf16_t* __restrict__ Yg, const int2* __restrict__ ids,
                    const int* __restrict__ slotA, const int* __restrict__ slotB,
                    const int* __restrict__ off, const float2* __restrict__ wts,
                    bf16_t* __restrict__ Xa){
  const int t = blockIdx.x, j = threadIdx.x*4;
  const int2 id = ids[t];
  const float2 w = wts[t];
  const bf16x4 a = *(const bf16x4*)(Yg + (size_t)(off[id.x] + slotA[t])*DD + j);
  const bf16x4 b = *(const bf16x4*)(Yg + (size_t)(off[id.y] + slotB[t])*DD + j);
  bf16x4 o;
  #pragma unroll
  for (int i = 0; i < 4; i++) o[i] = (bf16_t)(w.x*(float)a[i] + w.y*(float)b[i]);
  *(bf16x4*)(Xa + (size_t)t*DD + j) = o;
}

__global__ __launch_bounds__(256)
void mix_kernel(const float* __restrict__ x, const bf16_t* __restrict__ abel,
                const float* __restrict__ rot, const float* __restrict__ gcw,
                const float* __restrict__ gcb, float* __restrict__ out)
{
  const int t = blockIdx.x, tid = threadIdx.x, j0 = tid*4;
  const int wid = tid >> 6, lid = tid & 63;
  const bf16x4 ab = *(const bf16x4*)(abel + (size_t)t*DD + j0);
  const float4 r  = *(const float4*)(rot  + (size_t)t*DD + j0);
  const float4 ga = *(const float4*)(gcw + j0);
  const float4 gr = *(const float4*)(gcw + DD + j0);
  const float a0 = (float)ab[0], a1 = (float)ab[1], a2 = (float)ab[2], a3 = (float)ab[3];
  float p = a0*ga.x + a1*ga.y + a2*ga.z + a3*ga.w
          + r.x*gr.x + r.y*gr.y + r.z*gr.z + r.w*gr.w;
  #pragma unroll
  for (int off = 32; off; off >>= 1) p += __shfl_down(p, off);
  __shared__ float red[4];
  __shared__ float gsh;
  if (lid == 0) red[wid] = p;
  __syncthreads();
  if (tid == 0) {
    const float P = red[0] + red[1] + red[2] + red[3] + gcb[0];
    gsh = 1.0f/(1.0f + expf(-P));
  }
  __syncthreads();
  const float gate = gsh, g1 = 1.0f - gate;
  const float4 xv = *(const float4*)(x + (size_t)t*DD + j0);
  float4 o;
  o.x = xv.x + a0*g1 + r.x*gate;
  o.y = xv.y + a1*g1 + r.y*gate;
  o.z = xv.z + a2*g1 + r.z*gate;
  o.w = xv.w + a3*g1 + r.w*gate;
  *(float4*)(out + (size_t)t*DD + j0) = o;
}

extern "C" void kernel_launch(void* const* d_in, const int* in_sizes, int n_in,
                              void* d_out, int out_size, void* d_ws, size_t ws_size,
                              hipStream_t stream)
{
  (void)in_sizes; (void)n_in; (void)out_size; (void)ws_size;
  const float* x      = (const float*)d_in[0];
  const float* ln_g   = (const float*)d_in[1];
  const float* ln_b   = (const float*)d_in[2];
  const float* abel_w = (const float*)d_in[3];
  const float* abel_b = (const float*)d_in[4];
  const float* gate_w = (const float*)d_in[5];
  const float* gate_b = (const float*)d_in[6];
  const float* ew1    = (const float*)d_in[7];
  const float* eb1    = (const float*)d_in[8];
  const float* ew2    = (const float*)d_in[9];
  const float* eb2    = (const float*)d_in[10];
  const float* gens   = (const float*)d_in[11];
  const float* gc_w   = (const float*)d_in[12];
  const float* gc_b   = (const float*)d_in[13];
  float* out = (float*)d_out;

  char* wsp = (char*)d_ws;
  auto alloc = [&](size_t bytes) -> char* {
    char* p = wsp; wsp += (bytes + 255) & ~(size_t)255; return p;
  };
  const size_t MB = 1u<<20;
  bf16_t* xnb   = (bf16_t*)alloc((size_t)NTOK*DD*2);
  int2*   ids   = (int2*)  alloc((size_t)NTOK*8);
  float2* wts   = (float2*)alloc((size_t)NTOK*8);
  int*    slotA = (int*)   alloc((size_t)NTOK*4);
  int*    slotB = (int*)   alloc((size_t)NTOK*4);
  int*    cnt   = (int*)   alloc(64);
  int*    off   = (int*)   alloc(64);
  int*    tE1   = (int*)   alloc(MAXT1*4);
  int*    tR1   = (int*)   alloc(MAXT1*4);
  int*    tE2   = (int*)   alloc(MAXT2*4);
  int*    tR2   = (int*)   alloc(MAXT2*4);
  int*    ntp   = (int*)   alloc(64);
  int*    tokOf = (int*)   alloc((size_t)CAPR*4);
  bf16_t* abel_wT = (bf16_t*)alloc((size_t)DD*DD*2);
  char*   UN      = alloc(64*MB);            // ew1T(32MB)+ew2T(32MB); PS temps overlay
  bf16_t* ew1T  = (bf16_t*)UN;
  bf16_t* ew2T  = (bf16_t*)(UN + 32*MB);
  bf16_t* Hn    = (bf16_t*)alloc((size_t)3*DD*DD*2);
  bf16_t* abelo = (bf16_t*)alloc((size_t)NTOK*DD*2);
  bf16_t* Yg    = (bf16_t*)alloc((size_t)CAPR*DD*2);   // down output (gathered)
  bf16_t* Hg    = (bf16_t*)alloc((size_t)CAPR*DD2*2);  // up output; also rot(f32)
  bf16_t* Xa    = (bf16_t*)alloc((size_t)NTOK*DD*2);
  float*  rot   = (float*)Hg;
  // PS temps over UN (dead after up/down GEMMs)
  bf16_t* H2  = (bf16_t*)(UN + 0*MB);
  bf16_t* H3  = (bf16_t*)(UN + 6*MB);
  bf16_t* Vb  = (bf16_t*)(UN + 12*MB);
  bf16_t* Wtb = (bf16_t*)(UN + 18*MB);
  bf16_t* Ut  = (bf16_t*)(UN + 24*MB);
  bf16_t* Tb  = (bf16_t*)(UN + 30*MB);
  bf16_t* Pb  = (bf16_t*)(UN + 34*MB);
  bf16_t* Rt  = (bf16_t*)(UN + 36*MB);
  const long D2 = (long)DD*DD;

  auto gflat = [](int gx, int gy, int gz) {
    const int nwg = gx*gy*gz; return 8 * ((nwg + 7) / 8);
  };

  prep_kernel<<<dim3(11520,1,1), 256, 0, stream>>>(abel_w, abel_wT, ew1, ew1T,
                                                   ew2, ew2T, gens, Hn);
  ln_gate_kernel<<<dim3(NTOK,1,1), 256, 0, stream>>>(x, ln_g, ln_b, gate_w, gate_b,
                                                     xnb, ids, wts);
  route_kernel<<<dim3(1,1,1), 256, 0, stream>>>(ids, slotA, slotB, cnt, off,
                                                tE1, tR1, tE2, tR2, ntp);
  fill_tok_kernel<<<dim3(NTOK/256,1,1), 256, 0, stream>>>(ids, slotA, slotB, off, cnt, tokOf);

  // up-proj: 8-wave 256x256, 4-deep counted vmcnt + setprio (T3/T4/T5 analog)
  gemm_up8<<<dim3(gflat(DD2/256, MAXT2, 1),1,1), 512, 0, stream>>>(
      xnb, ew1T, DD2, DD, DD2/256, (long)DD2*DD,
      tE2, tR2, ntp + 1, off, tokOf, eb1, DD2, Hg);
  // down-proj: proven 4-wave 128x128 3-deep
  gemm_bt<128,128,EPI_BIAS_BF16,true><<<dim3(gflat(DD/128, MAXT1, 1),1,1), 256, 0, stream>>>(
      Hg, ew2T, DD, DD2, DD/128, MAXT1, 1, 0, (long)DD*DD2, 0,
      tE1, tR1, ntp, off, nullptr, eb2, DD, 1.0f, nullptr, nullptr, Yg);
  combine_kernel<<<dim3(NTOK,1,1), 256, 0, stream>>>(Yg, ids, slotA, slotB, off, wts, Xa);

  // abel branch: 128x64 (512 blocks = 2 blk/CU)
  gemm_bt<128,64,EPI_GELU_BF16,false><<<dim3(gflat(16,32,1),1,1), 256, 0, stream>>>(
      xnb, abel_wT, DD, DD, 16, 32, 1, 0, 0, 0, nullptr, nullptr, nullptr, nullptr,
      nullptr, abel_b, 0, 1.0f, nullptr, nullptr, abelo);

  // Degree-5 Paterson-Stockmeyer expm(H), H = -G (skew). 64x64 tiles.
  gemm_bt<64,64,EPI_SCALE_BF16,false><<<dim3(gflat(16,16,3),1,1), 256, 0, stream>>>(
      Hn, Hn, DD, DD, 16, 16, 3, D2, D2, D2, nullptr, nullptr, nullptr, nullptr,
      nullptr, nullptr, 0, -1.0f, nullptr, nullptr, H2);
  gemm_bt<64,64,EPI_SCALE_BF16,false><<<dim3(gflat(16,16,3),1,1), 256, 0, stream>>>(
      H2, Hn, DD, DD, 16, 16, 3, D2, D2, D2, nullptr, nullptr, nullptr, nullptr,
      nullptr, nullptr, 0, -1.0f, nullptr, nullptr, H3);
  vw_kernel<<<dim3(3*DD*DD/1024,1,1), 256, 0, stream>>>(Hn, H2, Vb, Wtb);
  gemm_bt<64,64,EPI_ADDV_BF16,false><<<dim3(gflat(16,16,3),1,1), 256, 0, stream>>>(
      H3, Wtb, DD, DD, 16, 16, 3, D2, D2, D2, nullptr, nullptr, nullptr, nullptr,
      nullptr, nullptr, 0, 1.0f, Vb, nullptr, Ut);
  // Rt = Ut2 @ Ut1 @ Ut0
  tb16_kernel<<<dim3(32,32,2), dim3(32,8,1), 0, stream>>>(Ut, Tb);
  gemm_bt<64,64,EPI_BF16,false><<<dim3(gflat(16,16,1),1,1), 256, 0, stream>>>(
      Ut + 2*D2, Tb, DD, DD, 16, 16, 1, 0, 0, 0, nullptr, nullptr, nullptr, nullptr,
      nullptr, nullptr, 0, 1.0f, nullptr, nullptr, Pb);
  gemm_bt<64,64,EPI_BF16,false><<<dim3(gflat(16,16,1),1,1), 256, 0, stream>>>(
      Pb, Tb + D2, DD, DD, 16, 16, 1, 0, 0, 0, nullptr, nullptr, nullptr, nullptr,
      nullptr, nullptr, 0, 1.0f, nullptr, nullptr, Rt);
  // rot = Xa @ Rt^T: 128x64
  gemm_bt<128,64,EPI_F32,false><<<dim3(gflat(16,32,1),1,1), 256, 0, stream>>>(
      Xa, Rt, DD, DD, 16, 32, 1, 0, 0, 0, nullptr, nullptr, nullptr, nullptr,
      nullptr, nullptr, 0, 1.0f, nullptr, rot, nullptr);

  mix_kernel<<<dim3(NTOK,1,1), 256, 0, stream>>>(x, abelo, rot, gc_w, gc_b, out);
}

// Round 19
// 328.120 us; speedup vs baseline: 1.0711x; 1.0711x over previous
//
#include <hip/hip_runtime.h>
#include <hip/hip_bf16.h>
#include <cstdint>
#include <cstddef>

#define DD   1024
#define DD2  2048
#define EE   8
#define NTOK 4096   // B*S
#define CAPR 9216   // max gathered rows: 2*NTOK + 8*128 alignment pad
#define MAXT 72     // max active 128-row tiles

typedef __bf16 bf16_t;
typedef __bf16 bf16x8 __attribute__((ext_vector_type(8)));
typedef __bf16 bf16x4 __attribute__((ext_vector_type(4)));
typedef float  f32x4v __attribute__((ext_vector_type(4)));

// tanh-form GELU (~1e-3 max err; slack is 3x)
__device__ __forceinline__ float gelu_f(float v){
  const float t = v*(0.7978845608028654f + 0.0356774081f*v*v);
  const float u = __expf(2.0f*t);
  return __fdividef(v*u, 1.0f + u);
}

__device__ __forceinline__ void gload_lds16(const void* g, void* l){
  __builtin_amdgcn_global_load_lds(
    (const __attribute__((address_space(1))) unsigned int*)(uintptr_t)g,
    (__attribute__((address_space(3))) unsigned int*)(uintptr_t)l,
    16, 0, 0);
}

enum { EPI_GELU_F32=0, EPI_GELU_BF16=1, EPI_BIAS_BF16=2, EPI_SCALE_BF16=3,
       EPI_ADDV_BF16=4, EPI_BF16=5, EPI_F32=6 };

// C = al*(A @ Bt^T) [+epi]. A:[M,K] bf16 rm, Bt:[N,K] bf16 rm. 4 waves, BK=32.
// 3-deep pipeline, counted vmcnt + raw s_barrier (T4): per step
//   vmcnt(NLD) -> barrier -> sched_barrier -> stage(t+2) -> MFMA(t).
// 128x128 = measured optimum for the big GEMMs; small GEMMs need >=2 blk/CU.
// TAB: compact-tile grouped MoE; tokOf row indirection fuses the gather.
// !TAB: m204 bijective XCD chunk swizzle.
template<int BM,int BN,int EPI,bool TAB>
__global__ __launch_bounds__(256)
void gemm_bt(const bf16_t* __restrict__ A, const bf16_t* __restrict__ Bt,
             const int N, const int K, const int gx, const int gy, const int gz,
             const long sAz, const long sBz, const long sOz,
             const int* __restrict__ tileE, const int* __restrict__ tileR,
             const int* __restrict__ ntp, const int* __restrict__ offp,
             const int* __restrict__ tokOf,
             const float* __restrict__ bias, const long sBias,
             const float alpha,
             const bf16_t* __restrict__ addv,
             float* __restrict__ outF, bf16_t* __restrict__ outB)
{
  constexpr int BK = 32;
  constexpr int WM = BM/2, WN = BN/2;
  constexpr int FM = WM/16, FN = WN/16;
  constexpr int IA = BM/64, IB = BN/64;   // gload insts per wave per stage
  constexpr int NLD = IA + IB;
  __shared__ alignas(16) bf16_t sA[3][BM*BK];
  __shared__ alignas(16) bf16_t sB[3][BN*BK];

  int bx, by, bz; long ro = 0;
  if constexpr (TAB) {
    const int nwg = gx * gy;             // gy = MAXT
    const int q = nwg >> 3, r = nwg & 7;
    const int k = blockIdx.x & 7, i = blockIdx.x >> 3;
    if (i >= q + (k < r ? 1 : 0)) return;
    const int l = k * q + (k < r ? k : r) + i;
    const int ti = l / gx; bx = l - ti*gx;
    if (ti >= ntp[0]) return;
    bz = tileE[ti]; by = 0;
    ro = (long)offp[bz] + tileR[ti];
  } else {
    const int nwg = gx * gy * gz;
    const int q = nwg >> 3, r = nwg & 7;
    const int k = blockIdx.x & 7, i = blockIdx.x >> 3;
    if (i >= q + (k < r ? 1 : 0)) return;
    const int l = k * q + (k < r ? k : r) + i;
    bx = l % gx; const int t2 = l / gx; by = t2 % gy; bz = t2 / gy;
  }

  const int z = bz;
  const bf16_t* Bp = Bt + (size_t)z * sBz;
  float*  oF = outF;
  bf16_t* oB = outB;
  if constexpr (TAB) {
    oB += ro * (long)N;
  } else {
    A += (size_t)z * sAz;
    if (oF) oF += (size_t)z * sOz;
    if (oB) oB += (size_t)z * sOz;
  }
  const float*  bp = bias ? bias + (size_t)z * sBias : nullptr;
  const bf16_t* vp = addv ? addv + (size_t)z * sOz   : nullptr;

  const int tid = threadIdx.x;
  const int wid = tid >> 6, lid = tid & 63;
  const int wr = wid >> 1, wc = wid & 1;
  const int brow = (TAB ? 0 : by * BM), bcol = bx * BN;
  const int fr = lid & 15, fq = lid >> 4;
  const int rl = lid >> 2, qs = lid & 3;   // staging: row-in-16-group, quad

  // per-lane pre-swizzled global sources (fixed across K-steps)
  const char* aSrc[IA];
  const char* bSrc[IB];
  #pragma unroll
  for (int i = 0; i < IA; i++) {
    const int rloc = (wid*IA + i)*16 + rl;
    const int q = qs ^ ((rloc >> 1) & 3);
    const bf16_t* arow;
    if constexpr (TAB) {
      arow = tokOf ? (A + (size_t)tokOf[ro + rloc] * K)
                   : (A + (size_t)(ro + rloc) * K);
    } else {
      arow = A + (size_t)(brow + rloc) * K;
    }
    aSrc[i] = (const char*)arow + q*16;
  }
  #pragma unroll
  for (int i = 0; i < IB; i++) {
    const int rloc = (wid*IB + i)*16 + rl;
    const int q = qs ^ ((rloc >> 1) & 3);
    bSrc[i] = (const char*)(Bp + (size_t)(bcol + rloc) * K) + q*16;
  }

  f32x4v acc[FM][FN] = {};

  auto stage = [&](int buf, int kt) {
    #pragma unroll
    for (int i = 0; i < IA; i++)
      gload_lds16(aSrc[i] + (size_t)kt*2, (char*)sA[buf] + (wid*IA + i)*1024);
    #pragma unroll
    for (int i = 0; i < IB; i++)
      gload_lds16(bSrc[i] + (size_t)kt*2, (char*)sB[buf] + (wid*IB + i)*1024);
  };

  stage(0, 0);
  stage(1, BK);
  const int nk = K / BK;
  int b0 = 0, b1 = 1, b2 = 2;

  for (int t = 0; t < nk; ++t) {
    if (t < nk - 1) asm volatile("s_waitcnt vmcnt(%0)" :: "i"(NLD) : "memory");
    else            asm volatile("s_waitcnt vmcnt(0)" ::: "memory");
    __builtin_amdgcn_s_barrier();
    __builtin_amdgcn_sched_barrier(0);
    if (t + 2 < nk) stage(b2, (t + 2)*BK);

    bf16x8 af[FM], bb[FN];
    #pragma unroll
    for (int mi = 0; mi < FM; mi++) {
      const int r2 = wr*WM + mi*16 + fr;
      const int q = fq ^ ((r2 >> 1) & 3);
      af[mi] = *(const bf16x8*)((const char*)sA[b0] + r2*64 + q*16);
    }
    #pragma unroll
    for (int ni = 0; ni < FN; ni++) {
      const int r2 = wc*WN + ni*16 + fr;
      const int q = fq ^ ((r2 >> 1) & 3);
      bb[ni] = *(const bf16x8*)((const char*)sB[b0] + r2*64 + q*16);
    }
    #pragma unroll
    for (int mi = 0; mi < FM; mi++)
      #pragma unroll
      for (int ni = 0; ni < FN; ni++)
        acc[mi][ni] = __builtin_amdgcn_mfma_f32_16x16x32_bf16(
            af[mi], bb[ni], acc[mi][ni], 0, 0, 0);

    const int tb_ = b0; b0 = b1; b1 = b2; b2 = tb_;
  }

  // C/D layout: col = lane&15, row = (lane>>4)*4 + i
  #pragma unroll
  for (int mi = 0; mi < FM; mi++) {
    #pragma unroll
    for (int ni = 0; ni < FN; ni++) {
      const int rg0 = brow + wr*WM + mi*16 + fq*4;
      const int cg  = bcol + wc*WN + ni*16 + fr;
      #pragma unroll
      for (int i = 0; i < 4; i++) {
        const int rg = rg0 + i;
        float v = acc[mi][ni][i];
        if constexpr (EPI == EPI_GELU_F32) {
          v += bp[cg];
          oF[(size_t)rg*N + cg] = gelu_f(v);
        } else if constexpr (EPI == EPI_GELU_BF16) {
          v += bp[cg];
          oB[(size_t)rg*N + cg] = (bf16_t)gelu_f(v);
        } else if constexpr (EPI == EPI_BIAS_BF16) {
          v += bp[cg];
          oB[(size_t)rg*N + cg] = (bf16_t)v;
        } else if constexpr (EPI == EPI_SCALE_BF16) {
          oB[(size_t)rg*N + cg] = (bf16_t)(v * alpha);
        } else if constexpr (EPI == EPI_ADDV_BF16) {
          oB[(size_t)rg*N + cg] = (bf16_t)(v + (float)vp[(size_t)rg*N + cg]);
        } else if constexpr (EPI == EPI_BF16) {
          oB[(size_t)rg*N + cg] = (bf16_t)v;
        } else {
          oF[(size_t)rg*N + cg] = v;
        }
      }
    }
  }
}

// ---- unified weight prep: one launch for all transposes + gens cvt ----
__device__ __forceinline__ void tcvt_tile(const float* __restrict__ src,
                                          bf16_t* __restrict__ dst,
                                          int R, int C, int bx, int by,
                                          float (*t)[65]){
  const int c0 = bx*64, r0 = by*64;
  const int lx = threadIdx.x & 15, ly = threadIdx.x >> 4;
  #pragma unroll
  for (int i = 0; i < 4; i++) {
    const int row = r0 + ly + i*16;
    const float4 v = *(const float4*)(src + (size_t)row*C + c0 + lx*4);
    t[ly + i*16][lx*4+0] = v.x; t[ly + i*16][lx*4+1] = v.y;
    t[ly + i*16][lx*4+2] = v.z; t[ly + i*16][lx*4+3] = v.w;
  }
  __syncthreads();
  #pragma unroll
  for (int i = 0; i < 4; i++) {
    const int c = c0 + ly + i*16;
    bf16x4 o;
    #pragma unroll
    for (int j = 0; j < 4; j++) o[j] = (bf16_t)t[lx*4+j][ly + i*16];
    *(bf16x4*)(dst + (size_t)c*R + r0 + lx*4) = o;
  }
}

// blocks [0,256): abel_wT; [256,4352): ew1T; [4352,8448): ew2T; [8448,11520): Hn=-gens
__global__ __launch_bounds__(256)
void prep_kernel(const float* __restrict__ abel_w, bf16_t* __restrict__ abel_wT,
                 const float* __restrict__ ew1, bf16_t* __restrict__ ew1T,
                 const float* __restrict__ ew2, bf16_t* __restrict__ ew2T,
                 const float* __restrict__ gens, bf16_t* __restrict__ Hn)
{
  __shared__ float t[64][65];
  const int bid = blockIdx.x;
  if (bid < 256) {
    tcvt_tile(abel_w, abel_wT, DD, DD, bid & 15, bid >> 4, t);
  } else if (bid < 4352) {
    const int i = bid - 256, z = i >> 9, r = i & 511;
    tcvt_tile(ew1 + (size_t)z*DD*DD2, ew1T + (size_t)z*DD2*DD, DD, DD2, r & 31, r >> 5, t);
  } else if (bid < 8448) {
    const int i = bid - 4352, z = i >> 9, r = i & 511;
    tcvt_tile(ew2 + (size_t)z*DD2*DD, ew2T + (size_t)z*DD*DD2, DD2, DD, r & 15, r >> 4, t);
  } else {
    const long i4 = ((long)(bid - 8448)*256 + threadIdx.x)*4;
    const float4 v = *(const float4*)(gens + i4);
    bf16x4 b; b[0]=(bf16_t)(-v.x); b[1]=(bf16_t)(-v.y);
    b[2]=(bf16_t)(-v.z); b[3]=(bf16_t)(-v.w);
    *(bf16x4*)(Hn + i4) = b;
  }
}

// bf16 [D,D] transpose: Tb[z] = Ut[1-z]^T  (z = 0,1)
__global__ __launch_bounds__(256)
void tb16_kernel(const bf16_t* __restrict__ Ut, bf16_t* __restrict__ Tb){
  __shared__ bf16_t tile[32][33];
  const bf16_t* src = Ut + (size_t)(1 - blockIdx.z) * DD * DD;
  bf16_t*       dst = Tb + (size_t)blockIdx.z * DD * DD;
  const int c0 = blockIdx.x*32, r0 = blockIdx.y*32;
  #pragma unroll
  for (int i = 0; i < 4; i++)
    tile[threadIdx.y + i*8][threadIdx.x] = src[(size_t)(r0 + threadIdx.y + i*8)*DD + c0 + threadIdx.x];
  __syncthreads();
  #pragma unroll
  for (int i = 0; i < 4; i++)
    dst[(size_t)(c0 + threadIdx.y + i*8)*DD + r0 + threadIdx.x] = tile[threadIdx.x][threadIdx.y + i*8];
}

// Degree-5 PS pieces: V = I + H + H2/2 ; Wt = I/6 - H/24 + H2/120
__global__ __launch_bounds__(256)
void vw_kernel(const bf16_t* __restrict__ Hn, const bf16_t* __restrict__ H2,
               bf16_t* __restrict__ Vb, bf16_t* __restrict__ Wtb){
  const long i0 = ((long)blockIdx.x*256 + threadIdx.x)*4;
  const long rc = i0 % (long)(DD*DD);
  const int r = (int)(rc / DD), c0 = (int)(rc % DD);
  const bf16x4 h  = *(const bf16x4*)(Hn + i0);
  const bf16x4 h2 = *(const bf16x4*)(H2 + i0);
  bf16x4 v, w;
  #pragma unroll
  for (int j = 0; j < 4; j++) {
    const float d  = (r == c0 + j) ? 1.0f : 0.0f;
    const float fh = (float)h[j], f2 = (float)h2[j];
    v[j] = (bf16_t)(d + fh + f2*0.5f);
    w[j] = (bf16_t)(d*(1.0f/6.0f) - fh*(1.0f/24.0f) + f2*(1.0f/120.0f));
  }
  *(bf16x4*)(Vb  + i0) = v;
  *(bf16x4*)(Wtb + i0) = w;
}

// LayerNorm -> xnb (bf16); gate logits -> per-token top-2 ids + softmax weights.
__global__ __launch_bounds__(256)
void ln_gate_kernel(const float* __restrict__ x, const float* __restrict__ gamma,
                    const float* __restrict__ beta, const float* __restrict__ gw,
                    const float* __restrict__ gb,
                    bf16_t* __restrict__ xnb, int2* __restrict__ ids,
                    float2* __restrict__ wts)
{
  const int t = blockIdx.x, tid = threadIdx.x, j0 = tid*4;
  const int wid = tid >> 6, lid = tid & 63;
  const float4 v = *(const float4*)(x + (size_t)t*DD + j0);
  float s  = v.x + v.y + v.z + v.w;
  float ss = v.x*v.x + v.y*v.y + v.z*v.z + v.w*v.w;
  #pragma unroll
  for (int off = 32; off; off >>= 1) { s += __shfl_down(s, off); ss += __shfl_down(ss, off); }
  __shared__ float redS[4], redQ[4], mv[2];
  if (lid == 0) { redS[wid] = s; redQ[wid] = ss; }
  __syncthreads();
  if (tid == 0) {
    const float S1 = redS[0]+redS[1]+redS[2]+redS[3];
    const float S2 = redQ[0]+redQ[1]+redQ[2]+redQ[3];
    const float mu  = S1 * (1.0f/DD);
    const float var = S2 * (1.0f/DD) - mu*mu;
    mv[0] = mu; mv[1] = rsqrtf(var + 1e-5f);
  }
  __syncthreads();
  const float mu = mv[0], rstd = mv[1];
  const float4 g = *(const float4*)(gamma + j0);
  const float4 b = *(const float4*)(beta  + j0);
  float xn[4];
  xn[0] = (v.x-mu)*rstd*g.x + b.x;
  xn[1] = (v.y-mu)*rstd*g.y + b.y;
  xn[2] = (v.z-mu)*rstd*g.z + b.z;
  xn[3] = (v.w-mu)*rstd*g.w + b.w;
  bf16x4 ov; ov[0]=(bf16_t)xn[0]; ov[1]=(bf16_t)xn[1]; ov[2]=(bf16_t)xn[2]; ov[3]=(bf16_t)xn[3];
  *(bf16x4*)(xnb + (size_t)t*DD + j0) = ov;

  float p[8] = {0,0,0,0,0,0,0,0};
  #pragma unroll
  for (int i = 0; i < 4; i++) {
    const float4 a0 = *(const float4*)(gw + (size_t)(j0+i)*EE);
    const float4 a1 = *(const float4*)(gw + (size_t)(j0+i)*EE + 4);
    const float xv = xn[i];
    p[0]+=xv*a0.x; p[1]+=xv*a0.y; p[2]+=xv*a0.z; p[3]+=xv*a0.w;
    p[4]+=xv*a1.x; p[5]+=xv*a1.y; p[6]+=xv*a1.z; p[7]+=xv*a1.w;
  }
  #pragma unroll
  for (int off = 32; off; off >>= 1) {
    #pragma unroll
    for (int e = 0; e < 8; e++) p[e] += __shfl_down(p[e], off);
  }
  __shared__ float pr[32];
  if (lid == 0) {
    #pragma unroll
    for (int e = 0; e < 8; e++) pr[wid*8 + e] = p[e];
  }
  __syncthreads();
  if (tid == 0) {
    float l[8];
    #pragma unroll
    for (int e = 0; e < 8; e++) l[e] = pr[e] + pr[8+e] + pr[16+e] + pr[24+e] + gb[e];
    int i1 = 0; float m1 = l[0];
    #pragma unroll
    for (int e = 1; e < 8; e++) if (l[e] > m1) { m1 = l[e]; i1 = e; }
    int i2 = 0; float m2 = -1e30f;
    #pragma unroll
    for (int e = 0; e < 8; e++) if (e != i1 && l[e] > m2) { m2 = l[e]; i2 = e; }
    const float wa = 1.0f/(1.0f + expf(m2 - m1));  // softmax over top-2
    ids[t] = make_int2(i1, i2);
    wts[t] = make_float2(wa, 1.0f - wa);
  }
}

// Deterministic slot assignment (ballot-scan), 128-aligned prefix offsets,
// and the compact active-tile table. No atomics, one launch.
__global__ __launch_bounds__(256)
void route_kernel(const int2* __restrict__ ids, int* __restrict__ slotA,
                  int* __restrict__ slotB, int* __restrict__ cnt,
                  int* __restrict__ off, int* __restrict__ tileE,
                  int* __restrict__ tileR, int* __restrict__ ntp)
{
  const int tid = threadIdx.x;
  const int wid = tid >> 6, lid = tid & 63;
  __shared__ int wsum[EE][4];
  __shared__ int base[EE];
  if (tid < EE) base[tid] = 0;
  __syncthreads();
  const unsigned long long lt = (1ull << lid) - 1ull;
  for (int c0 = 0; c0 < NTOK; c0 += 256) {
    const int t = c0 + tid;
    const int2 id = ids[t];
    int pA = 0, pB = 0;
    #pragma unroll
    for (int e = 0; e < EE; e++) {
      const bool fA = (id.x == e), fB = (id.y == e);
      const unsigned long long mA = __ballot(fA);
      const unsigned long long mB = __ballot(fB);
      const int cA = __popcll(mA);
      if (lid == 0) wsum[e][wid] = cA + __popcll(mB);
      if (fA) pA = __popcll(mA & lt);
      if (fB) pB = cA + __popcll(mB & lt);
    }
    __syncthreads();
    int wbA = base[id.x], wbB = base[id.y];
    for (int w = 0; w < wid; w++) { wbA += wsum[id.x][w]; wbB += wsum[id.y][w]; }
    slotA[t] = wbA + pA;
    slotB[t] = wbB + pB;
    __syncthreads();
    if (tid < EE) base[tid] += wsum[tid][0]+wsum[tid][1]+wsum[tid][2]+wsum[tid][3];
    __syncthreads();
  }
  if (tid == 0) {
    int a = 0, nt = 0;
    for (int e = 0; e < EE; e++) {
      cnt[e] = base[e]; off[e] = a;
      for (int r2 = 0; r2 < base[e]; r2 += 128) { tileE[nt] = e; tileR[nt] = r2; nt++; }
      a += (base[e] + 127) & ~127;
    }
    ntp[0] = nt;
  }
}

// tokOf[gathered_row] = token; block 0 zeroes pad rows (disjoint addresses).
__global__ __launch_bounds__(256)
void fill_tok_kernel(const int2* __restrict__ ids, const int* __restrict__ slotA,
                     const int* __restrict__ slotB, const int* __restrict__ off,
                     const int* __restrict__ cnt, int* __restrict__ tokOf){
  const int t = blockIdx.x*256 + threadIdx.x;
  const int2 id = ids[t];
  tokOf[off[id.x] + slotA[t]] = t;
  tokOf[off[id.y] + slotB[t]] = t;
  if (blockIdx.x == 0) {
    for (int e = 0; e < EE; e++) {
      const int c = cnt[e], o = off[e], al = (c + 127) & ~127;
      for (int p = c + threadIdx.x; p < al; p += 256) tokOf[o + p] = 0;
    }
  }
}

// Xa[t] = bf16(w1*Yg[loc1] + w2*Yg[loc2])
__global__ __launch_bounds__(256)
void combine_kernel(const bf16_t* __restrict__ Yg, const int2* __restrict__ ids,
                    const int* __restrict__ slotA, const int* __restrict__ slotB,
                    const int* __restrict__ off, const float2* __restrict__ wts,
                    bf16_t* __restrict__ Xa){
  const int t = blockIdx.x, j = threadIdx.x*4;
  const int2 id = ids[t];
  const float2 w = wts[t];
  const bf16x4 a = *(const bf16x4*)(Yg + (size_t)(off[id.x] + slotA[t])*DD + j);
  const bf16x4 b = *(const bf16x4*)(Yg + (size_t)(off[id.y] + slotB[t])*DD + j);
  bf16x4 o;
  #pragma unroll
  for (int i = 0; i < 4; i++) o[i] = (bf16_t)(w.x*(float)a[i] + w.y*(float)b[i]);
  *(bf16x4*)(Xa + (size_t)t*DD + j) = o;
}

__global__ __launch_bounds__(256)
void mix_kernel(const float* __restrict__ x, const bf16_t* __restrict__ abel,
                const float* __restrict__ rot, const float* __restrict__ gcw,
                const float* __restrict__ gcb, float* __restrict__ out)
{
  const int t = blockIdx.x, tid = threadIdx.x, j0 = tid*4;
  const int wid = tid >> 6, lid = tid & 63;
  const bf16x4 ab = *(const bf16x4*)(abel + (size_t)t*DD + j0);
  const float4 r  = *(const float4*)(rot  + (size_t)t*DD + j0);
  const float4 ga = *(const float4*)(gcw + j0);
  const float4 gr = *(const float4*)(gcw + DD + j0);
  const float a0 = (float)ab[0], a1 = (float)ab[1], a2 = (float)ab[2], a3 = (float)ab[3];
  float p = a0*ga.x + a1*ga.y + a2*ga.z + a3*ga.w
          + r.x*gr.x + r.y*gr.y + r.z*gr.z + r.w*gr.w;
  #pragma unroll
  for (int off = 32; off; off >>= 1) p += __shfl_down(p, off);
  __shared__ float red[4];
  __shared__ float gsh;
  if (lid == 0) red[wid] = p;
  __syncthreads();
  if (tid == 0) {
    const float P = red[0] + red[1] + red[2] + red[3] + gcb[0];
    gsh = 1.0f/(1.0f + expf(-P));
  }
  __syncthreads();
  const float gate = gsh, g1 = 1.0f - gate;
  const float4 xv = *(const float4*)(x + (size_t)t*DD + j0);
  float4 o;
  o.x = xv.x + a0*g1 + r.x*gate;
  o.y = xv.y + a1*g1 + r.y*gate;
  o.z = xv.z + a2*g1 + r.z*gate;
  o.w = xv.w + a3*g1 + r.w*gate;
  *(float4*)(out + (size_t)t*DD + j0) = o;
}

extern "C" void kernel_launch(void* const* d_in, const int* in_sizes, int n_in,
                              void* d_out, int out_size, void* d_ws, size_t ws_size,
                              hipStream_t stream)
{
  (void)in_sizes; (void)n_in; (void)out_size; (void)ws_size;
  const float* x      = (const float*)d_in[0];
  const float* ln_g   = (const float*)d_in[1];
  const float* ln_b   = (const float*)d_in[2];
  const float* abel_w = (const float*)d_in[3];
  const float* abel_b = (const float*)d_in[4];
  const float* gate_w = (const float*)d_in[5];
  const float* gate_b = (const float*)d_in[6];
  const float* ew1    = (const float*)d_in[7];
  const float* eb1    = (const float*)d_in[8];
  const float* ew2    = (const float*)d_in[9];
  const float* eb2    = (const float*)d_in[10];
  const float* gens   = (const float*)d_in[11];
  const float* gc_w   = (const float*)d_in[12];
  const float* gc_b   = (const float*)d_in[13];
  float* out = (float*)d_out;

  char* wsp = (char*)d_ws;
  auto alloc = [&](size_t bytes) -> char* {
    char* p = wsp; wsp += (bytes + 255) & ~(size_t)255; return p;
  };
  const size_t MB = 1u<<20;
  bf16_t* xnb   = (bf16_t*)alloc((size_t)NTOK*DD*2);
  int2*   ids   = (int2*)  alloc((size_t)NTOK*8);
  float2* wts   = (float2*)alloc((size_t)NTOK*8);
  int*    slotA = (int*)   alloc((size_t)NTOK*4);
  int*    slotB = (int*)   alloc((size_t)NTOK*4);
  int*    cnt   = (int*)   alloc(64);
  int*    off   = (int*)   alloc(64);
  int*    tileE = (int*)   alloc(MAXT*4);
  int*    tileR = (int*)   alloc(MAXT*4);
  int*    ntp   = (int*)   alloc(64);
  int*    tokOf = (int*)   alloc((size_t)CAPR*4);
  bf16_t* abel_wT = (bf16_t*)alloc((size_t)DD*DD*2);
  char*   UN      = alloc(64*MB);            // ew1T(32MB)+ew2T(32MB); PS temps overlay
  bf16_t* ew1T  = (bf16_t*)UN;
  bf16_t* ew2T  = (bf16_t*)(UN + 32*MB);
  bf16_t* Hn    = (bf16_t*)alloc((size_t)3*DD*DD*2);
  bf16_t* abelo = (bf16_t*)alloc((size_t)NTOK*DD*2);
  bf16_t* Yg    = (bf16_t*)alloc((size_t)CAPR*DD*2);   // down output (gathered)
  bf16_t* Hg    = (bf16_t*)alloc((size_t)CAPR*DD2*2);  // up output; also rot(f32)
  bf16_t* Xa    = (bf16_t*)alloc((size_t)NTOK*DD*2);
  float*  rot   = (float*)Hg;
  // PS temps over UN (dead after up/down GEMMs)
  bf16_t* H2  = (bf16_t*)(UN + 0*MB);
  bf16_t* H3  = (bf16_t*)(UN + 6*MB);
  bf16_t* Vb  = (bf16_t*)(UN + 12*MB);
  bf16_t* Wtb = (bf16_t*)(UN + 18*MB);
  bf16_t* Ut  = (bf16_t*)(UN + 24*MB);
  bf16_t* Tb  = (bf16_t*)(UN + 30*MB);
  bf16_t* Pb  = (bf16_t*)(UN + 34*MB);
  bf16_t* Rt  = (bf16_t*)(UN + 36*MB);
  const long D2 = (long)DD*DD;

  auto gflat = [](int gx, int gy, int gz) {
    const int nwg = gx*gy*gz; return 8 * ((nwg + 7) / 8);
  };

  // one launch: abel_wT + ew1T + ew2T transposes + Hn = -gens (bf16)
  prep_kernel<<<dim3(11520,1,1), 256, 0, stream>>>(abel_w, abel_wT, ew1, ew1T,
                                                   ew2, ew2T, gens, Hn);

  ln_gate_kernel<<<dim3(NTOK,1,1), 256, 0, stream>>>(x, ln_g, ln_b, gate_w, gate_b,
                                                     xnb, ids, wts);
  route_kernel<<<dim3(1,1,1), 256, 0, stream>>>(ids, slotA, slotB, cnt, off,
                                                tileE, tileR, ntp);
  fill_tok_kernel<<<dim3(NTOK/256,1,1), 256, 0, stream>>>(ids, slotA, slotB, off, cnt, tokOf);

  // sparse MoE: 128x128 3-deep (measured optimum); fused gather via tokOf
  gemm_bt<128,128,EPI_GELU_BF16,true><<<dim3((DD2/128)*MAXT,1,1), 256, 0, stream>>>(
      xnb, ew1T, DD2, DD, DD2/128, MAXT, 1, 0, (long)DD2*DD, 0,
      tileE, tileR, ntp, off, tokOf, eb1, DD2, 1.0f, nullptr, nullptr, Hg);
  gemm_bt<128,128,EPI_BIAS_BF16,true><<<dim3((DD/128)*MAXT,1,1), 256, 0, stream>>>(
      Hg, ew2T, DD, DD2, DD/128, MAXT, 1, 0, (long)DD*DD2, 0,
      tileE, tileR, ntp, off, nullptr, eb2, DD, 1.0f, nullptr, nullptr, Yg);
  combine_kernel<<<dim3(NTOK,1,1), 256, 0, stream>>>(Yg, ids, slotA, slotB, off, wts, Xa);

  // abel branch: 128x64 -> 512 blocks = 2 blk/CU
  gemm_bt<128,64,EPI_GELU_BF16,false><<<dim3(gflat(16,32,1),1,1), 256, 0, stream>>>(
      xnb, abel_wT, DD, DD, 16, 32, 1, 0, 0, 0, nullptr, nullptr, nullptr, nullptr,
      nullptr, abel_b, 0, 1.0f, nullptr, nullptr, abelo);

  // Degree-5 Paterson-Stockmeyer expm(H), H = -G (skew). 64x64 tiles.
  gemm_bt<64,64,EPI_SCALE_BF16,false><<<dim3(gflat(16,16,3),1,1), 256, 0, stream>>>(
      Hn, Hn, DD, DD, 16, 16, 3, D2, D2, D2, nullptr, nullptr, nullptr, nullptr,
      nullptr, nullptr, 0, -1.0f, nullptr, nullptr, H2);
  gemm_bt<64,64,EPI_SCALE_BF16,false><<<dim3(gflat(16,16,3),1,1), 256, 0, stream>>>(
      H2, Hn, DD, DD, 16, 16, 3, D2, D2, D2, nullptr, nullptr, nullptr, nullptr,
      nullptr, nullptr, 0, -1.0f, nullptr, nullptr, H3);
  vw_kernel<<<dim3(3*DD*DD/1024,1,1), 256, 0, stream>>>(Hn, H2, Vb, Wtb);
  gemm_bt<64,64,EPI_ADDV_BF16,false><<<dim3(gflat(16,16,3),1,1), 256, 0, stream>>>(
      H3, Wtb, DD, DD, 16, 16, 3, D2, D2, D2, nullptr, nullptr, nullptr, nullptr,
      nullptr, nullptr, 0, 1.0f, Vb, nullptr, Ut);
  // Rt = Ut2 @ Ut1 @ Ut0
  tb16_kernel<<<dim3(32,32,2), dim3(32,8,1), 0, stream>>>(Ut, Tb);
  gemm_bt<64,64,EPI_BF16,false><<<dim3(gflat(16,16,1),1,1), 256, 0, stream>>>(
      Ut + 2*D2, Tb, DD, DD, 16, 16, 1, 0, 0, 0, nullptr, nullptr, nullptr, nullptr,
      nullptr, nullptr, 0, 1.0f, nullptr, nullptr, Pb);
  gemm_bt<64,64,EPI_BF16,false><<<dim3(gflat(16,16,1),1,1), 256, 0, stream>>>(
      Pb, Tb + D2, DD, DD, 16, 16, 1, 0, 0, 0, nullptr, nullptr, nullptr, nullptr,
      nullptr, nullptr, 0, 1.0f, nullptr, nullptr, Rt);
  // rot = Xa @ Rt^T: 128x64 -> 512 blocks = 2 blk/CU
  gemm_bt<128,64,EPI_F32,false><<<dim3(gflat(16,32,1),1,1), 256, 0, stream>>>(
      Xa, Rt, DD, DD, 16, 32, 1, 0, 0, 0, nullptr, nullptr, nullptr, nullptr,
      nullptr, nullptr, 0, 1.0f, nullptr, rot, nullptr);

  mix_kernel<<<dim3(NTOK,1,1), 256, 0, stream>>>(x, abelo, rot, gc_w, gc_b, out);
}

// Round 20
// 327.146 us; speedup vs baseline: 1.0743x; 1.0030x over previous
//
#include <hip/hip_runtime.h>
#include <hip/hip_bf16.h>
#include <cstdint>
#include <cstddef>

#define DD   1024
#define DD2  2048
#define EE   8
#define NTOK 4096   // B*S
#define CAPR 9216   // max gathered rows: 2*NTOK + 8*128 alignment pad
#define MAXT 72     // max active 128-row tiles

typedef __bf16 bf16_t;
typedef __bf16 bf16x8 __attribute__((ext_vector_type(8)));
typedef __bf16 bf16x4 __attribute__((ext_vector_type(4)));
typedef float  f32x4v __attribute__((ext_vector_type(4)));

// tanh-form GELU (~1e-3 max err; slack is 3x)
__device__ __forceinline__ float gelu_f(float v){
  const float t = v*(0.7978845608028654f + 0.0356774081f*v*v);
  const float u = __expf(2.0f*t);
  return __fdividef(v*u, 1.0f + u);
}

__device__ __forceinline__ void gload_lds16(const void* g, void* l){
  __builtin_amdgcn_global_load_lds(
    (const __attribute__((address_space(1))) unsigned int*)(uintptr_t)g,
    (__attribute__((address_space(3))) unsigned int*)(uintptr_t)l,
    16, 0, 0);
}

enum { EPI_GELU_F32=0, EPI_GELU_BF16=1, EPI_BIAS_BF16=2, EPI_SCALE_BF16=3,
       EPI_ADDV_BF16=4, EPI_BF16=5, EPI_F32=6 };

// C = al*(A @ Bt^T) [+epi]. A:[M,K] bf16 rm, Bt:[N,K] bf16 rm. 4 waves, BK=32.
// 3-deep pipeline, counted vmcnt + raw s_barrier (T4): per step
//   vmcnt(NLD) -> barrier -> sched_barrier -> stage(t+2) -> MFMA(t).
// 128x128 = measured optimum for the big GEMMs; small GEMMs need >=2 blk/CU.
// TAB: compact-tile grouped MoE; tokOf row indirection fuses the gather.
// !TAB: m204 bijective XCD chunk swizzle.
template<int BM,int BN,int EPI,bool TAB>
__global__ __launch_bounds__(256)
void gemm_bt(const bf16_t* __restrict__ A, const bf16_t* __restrict__ Bt,
             const int N, const int K, const int gx, const int gy, const int gz,
             const long sAz, const long sBz, const long sOz,
             const int* __restrict__ tileE, const int* __restrict__ tileR,
             const int* __restrict__ ntp, const int* __restrict__ offp,
             const int* __restrict__ tokOf,
             const float* __restrict__ bias, const long sBias,
             const float alpha,
             const bf16_t* __restrict__ addv,
             float* __restrict__ outF, bf16_t* __restrict__ outB)
{
  constexpr int BK = 32;
  constexpr int WM = BM/2, WN = BN/2;
  constexpr int FM = WM/16, FN = WN/16;
  constexpr int IA = BM/64, IB = BN/64;   // gload insts per wave per stage
  constexpr int NLD = IA + IB;
  __shared__ alignas(16) bf16_t sA[3][BM*BK];
  __shared__ alignas(16) bf16_t sB[3][BN*BK];

  int bx, by, bz; long ro = 0;
  if constexpr (TAB) {
    const int nwg = gx * gy;             // gy = MAXT
    const int q = nwg >> 3, r = nwg & 7;
    const int k = blockIdx.x & 7, i = blockIdx.x >> 3;
    if (i >= q + (k < r ? 1 : 0)) return;
    const int l = k * q + (k < r ? k : r) + i;
    const int ti = l / gx; bx = l - ti*gx;
    if (ti >= ntp[0]) return;
    bz = tileE[ti]; by = 0;
    ro = (long)offp[bz] + tileR[ti];
  } else {
    const int nwg = gx * gy * gz;
    const int q = nwg >> 3, r = nwg & 7;
    const int k = blockIdx.x & 7, i = blockIdx.x >> 3;
    if (i >= q + (k < r ? 1 : 0)) return;
    const int l = k * q + (k < r ? k : r) + i;
    bx = l % gx; const int t2 = l / gx; by = t2 % gy; bz = t2 / gy;
  }

  const int z = bz;
  const bf16_t* Bp = Bt + (size_t)z * sBz;
  float*  oF = outF;
  bf16_t* oB = outB;
  if constexpr (TAB) {
    oB += ro * (long)N;
  } else {
    A += (size_t)z * sAz;
    if (oF) oF += (size_t)z * sOz;
    if (oB) oB += (size_t)z * sOz;
  }
  const float*  bp = bias ? bias + (size_t)z * sBias : nullptr;
  const bf16_t* vp = addv ? addv + (size_t)z * sOz   : nullptr;

  const int tid = threadIdx.x;
  const int wid = tid >> 6, lid = tid & 63;
  const int wr = wid >> 1, wc = wid & 1;
  const int brow = (TAB ? 0 : by * BM), bcol = bx * BN;
  const int fr = lid & 15, fq = lid >> 4;
  const int rl = lid >> 2, qs = lid & 3;   // staging: row-in-16-group, quad

  // per-lane pre-swizzled global sources (fixed across K-steps)
  const char* aSrc[IA];
  const char* bSrc[IB];
  #pragma unroll
  for (int i = 0; i < IA; i++) {
    const int rloc = (wid*IA + i)*16 + rl;
    const int q = qs ^ ((rloc >> 1) & 3);
    const bf16_t* arow;
    if constexpr (TAB) {
      arow = tokOf ? (A + (size_t)tokOf[ro + rloc] * K)
                   : (A + (size_t)(ro + rloc) * K);
    } else {
      arow = A + (size_t)(brow + rloc) * K;
    }
    aSrc[i] = (const char*)arow + q*16;
  }
  #pragma unroll
  for (int i = 0; i < IB; i++) {
    const int rloc = (wid*IB + i)*16 + rl;
    const int q = qs ^ ((rloc >> 1) & 3);
    bSrc[i] = (const char*)(Bp + (size_t)(bcol + rloc) * K) + q*16;
  }

  f32x4v acc[FM][FN] = {};

  auto stage = [&](int buf, int kt) {
    #pragma unroll
    for (int i = 0; i < IA; i++)
      gload_lds16(aSrc[i] + (size_t)kt*2, (char*)sA[buf] + (wid*IA + i)*1024);
    #pragma unroll
    for (int i = 0; i < IB; i++)
      gload_lds16(bSrc[i] + (size_t)kt*2, (char*)sB[buf] + (wid*IB + i)*1024);
  };

  stage(0, 0);
  stage(1, BK);
  const int nk = K / BK;
  int b0 = 0, b1 = 1, b2 = 2;

  for (int t = 0; t < nk; ++t) {
    if (t < nk - 1) asm volatile("s_waitcnt vmcnt(%0)" :: "i"(NLD) : "memory");
    else            asm volatile("s_waitcnt vmcnt(0)" ::: "memory");
    __builtin_amdgcn_s_barrier();
    __builtin_amdgcn_sched_barrier(0);
    if (t + 2 < nk) stage(b2, (t + 2)*BK);

    bf16x8 af[FM], bb[FN];
    #pragma unroll
    for (int mi = 0; mi < FM; mi++) {
      const int r2 = wr*WM + mi*16 + fr;
      const int q = fq ^ ((r2 >> 1) & 3);
      af[mi] = *(const bf16x8*)((const char*)sA[b0] + r2*64 + q*16);
    }
    #pragma unroll
    for (int ni = 0; ni < FN; ni++) {
      const int r2 = wc*WN + ni*16 + fr;
      const int q = fq ^ ((r2 >> 1) & 3);
      bb[ni] = *(const bf16x8*)((const char*)sB[b0] + r2*64 + q*16);
    }
    #pragma unroll
    for (int mi = 0; mi < FM; mi++)
      #pragma unroll
      for (int ni = 0; ni < FN; ni++)
        acc[mi][ni] = __builtin_amdgcn_mfma_f32_16x16x32_bf16(
            af[mi], bb[ni], acc[mi][ni], 0, 0, 0);

    const int tb_ = b0; b0 = b1; b1 = b2; b2 = tb_;
  }

  // C/D layout: col = lane&15, row = (lane>>4)*4 + i
  #pragma unroll
  for (int mi = 0; mi < FM; mi++) {
    #pragma unroll
    for (int ni = 0; ni < FN; ni++) {
      const int rg0 = brow + wr*WM + mi*16 + fq*4;
      const int cg  = bcol + wc*WN + ni*16 + fr;
      #pragma unroll
      for (int i = 0; i < 4; i++) {
        const int rg = rg0 + i;
        float v = acc[mi][ni][i];
        if constexpr (EPI == EPI_GELU_F32) {
          v += bp[cg];
          oF[(size_t)rg*N + cg] = gelu_f(v);
        } else if constexpr (EPI == EPI_GELU_BF16) {
          v += bp[cg];
          oB[(size_t)rg*N + cg] = (bf16_t)gelu_f(v);
        } else if constexpr (EPI == EPI_BIAS_BF16) {
          v += bp[cg];
          oB[(size_t)rg*N + cg] = (bf16_t)v;
        } else if constexpr (EPI == EPI_SCALE_BF16) {
          oB[(size_t)rg*N + cg] = (bf16_t)(v * alpha);
        } else if constexpr (EPI == EPI_ADDV_BF16) {
          oB[(size_t)rg*N + cg] = (bf16_t)(v + (float)vp[(size_t)rg*N + cg]);
        } else if constexpr (EPI == EPI_BF16) {
          oB[(size_t)rg*N + cg] = (bf16_t)v;
        } else {
          oF[(size_t)rg*N + cg] = v;
        }
      }
    }
  }
}

// ---- unified weight prep: one launch for all transposes + gens cvt ----
__device__ __forceinline__ void tcvt_tile(const float* __restrict__ src,
                                          bf16_t* __restrict__ dst,
                                          int R, int C, int bx, int by,
                                          float (*t)[65]){
  const int c0 = bx*64, r0 = by*64;
  const int lx = threadIdx.x & 15, ly = threadIdx.x >> 4;
  #pragma unroll
  for (int i = 0; i < 4; i++) {
    const int row = r0 + ly + i*16;
    const float4 v = *(const float4*)(src + (size_t)row*C + c0 + lx*4);
    t[ly + i*16][lx*4+0] = v.x; t[ly + i*16][lx*4+1] = v.y;
    t[ly + i*16][lx*4+2] = v.z; t[ly + i*16][lx*4+3] = v.w;
  }
  __syncthreads();
  #pragma unroll
  for (int i = 0; i < 4; i++) {
    const int c = c0 + ly + i*16;
    bf16x4 o;
    #pragma unroll
    for (int j = 0; j < 4; j++) o[j] = (bf16_t)t[lx*4+j][ly + i*16];
    *(bf16x4*)(dst + (size_t)c*R + r0 + lx*4) = o;
  }
}

// blocks [0,256): abel_wT; [256,4352): ew1T; [4352,8448): ew2T; [8448,11520): Hn=-gens
__global__ __launch_bounds__(256)
void prep_kernel(const float* __restrict__ abel_w, bf16_t* __restrict__ abel_wT,
                 const float* __restrict__ ew1, bf16_t* __restrict__ ew1T,
                 const float* __restrict__ ew2, bf16_t* __restrict__ ew2T,
                 const float* __restrict__ gens, bf16_t* __restrict__ Hn)
{
  __shared__ float t[64][65];
  const int bid = blockIdx.x;
  if (bid < 256) {
    tcvt_tile(abel_w, abel_wT, DD, DD, bid & 15, bid >> 4, t);
  } else if (bid < 4352) {
    const int i = bid - 256, z = i >> 9, r = i & 511;
    tcvt_tile(ew1 + (size_t)z*DD*DD2, ew1T + (size_t)z*DD2*DD, DD, DD2, r & 31, r >> 5, t);
  } else if (bid < 8448) {
    const int i = bid - 4352, z = i >> 9, r = i & 511;
    tcvt_tile(ew2 + (size_t)z*DD2*DD, ew2T + (size_t)z*DD*DD2, DD2, DD, r & 15, r >> 4, t);
  } else {
    const long i4 = ((long)(bid - 8448)*256 + threadIdx.x)*4;
    const float4 v = *(const float4*)(gens + i4);
    bf16x4 b; b[0]=(bf16_t)(-v.x); b[1]=(bf16_t)(-v.y);
    b[2]=(bf16_t)(-v.z); b[3]=(bf16_t)(-v.w);
    *(bf16x4*)(Hn + i4) = b;
  }
}

// bf16 [D,D] transpose: Tb[z] = Ut[1-z]^T  (z = 0,1)
__global__ __launch_bounds__(256)
void tb16_kernel(const bf16_t* __restrict__ Ut, bf16_t* __restrict__ Tb){
  __shared__ bf16_t tile[32][33];
  const bf16_t* src = Ut + (size_t)(1 - blockIdx.z) * DD * DD;
  bf16_t*       dst = Tb + (size_t)blockIdx.z * DD * DD;
  const int c0 = blockIdx.x*32, r0 = blockIdx.y*32;
  #pragma unroll
  for (int i = 0; i < 4; i++)
    tile[threadIdx.y + i*8][threadIdx.x] = src[(size_t)(r0 + threadIdx.y + i*8)*DD + c0 + threadIdx.x];
  __syncthreads();
  #pragma unroll
  for (int i = 0; i < 4; i++)
    dst[(size_t)(c0 + threadIdx.y + i*8)*DD + r0 + threadIdx.x] = tile[threadIdx.x][threadIdx.y + i*8];
}

// Degree-5 PS pieces: V = I + H + H2/2 ; Wt = I/6 - H/24 + H2/120
__global__ __launch_bounds__(256)
void vw_kernel(const bf16_t* __restrict__ Hn, const bf16_t* __restrict__ H2,
               bf16_t* __restrict__ Vb, bf16_t* __restrict__ Wtb){
  const long i0 = ((long)blockIdx.x*256 + threadIdx.x)*4;
  const long rc = i0 % (long)(DD*DD);
  const int r = (int)(rc / DD), c0 = (int)(rc % DD);
  const bf16x4 h  = *(const bf16x4*)(Hn + i0);
  const bf16x4 h2 = *(const bf16x4*)(H2 + i0);
  bf16x4 v, w;
  #pragma unroll
  for (int j = 0; j < 4; j++) {
    const float d  = (r == c0 + j) ? 1.0f : 0.0f;
    const float fh = (float)h[j], f2 = (float)h2[j];
    v[j] = (bf16_t)(d + fh + f2*0.5f);
    w[j] = (bf16_t)(d*(1.0f/6.0f) - fh*(1.0f/24.0f) + f2*(1.0f/120.0f));
  }
  *(bf16x4*)(Vb  + i0) = v;
  *(bf16x4*)(Wtb + i0) = w;
}

// LayerNorm -> xnb (bf16); gate logits -> per-token top-2 ids + softmax weights.
__global__ __launch_bounds__(256)
void ln_gate_kernel(const float* __restrict__ x, const float* __restrict__ gamma,
                    const float* __restrict__ beta, const float* __restrict__ gw,
                    const float* __restrict__ gb,
                    bf16_t* __restrict__ xnb, int2* __restrict__ ids,
                    float2* __restrict__ wts)
{
  const int t = blockIdx.x, tid = threadIdx.x, j0 = tid*4;
  const int wid = tid >> 6, lid = tid & 63;
  const float4 v = *(const float4*)(x + (size_t)t*DD + j0);
  float s  = v.x + v.y + v.z + v.w;
  float ss = v.x*v.x + v.y*v.y + v.z*v.z + v.w*v.w;
  #pragma unroll
  for (int off = 32; off; off >>= 1) { s += __shfl_down(s, off); ss += __shfl_down(ss, off); }
  __shared__ float redS[4], redQ[4], mv[2];
  if (lid == 0) { redS[wid] = s; redQ[wid] = ss; }
  __syncthreads();
  if (tid == 0) {
    const float S1 = redS[0]+redS[1]+redS[2]+redS[3];
    const float S2 = redQ[0]+redQ[1]+redQ[2]+redQ[3];
    const float mu  = S1 * (1.0f/DD);
    const float var = S2 * (1.0f/DD) - mu*mu;
    mv[0] = mu; mv[1] = rsqrtf(var + 1e-5f);
  }
  __syncthreads();
  const float mu = mv[0], rstd = mv[1];
  const float4 g = *(const float4*)(gamma + j0);
  const float4 b = *(const float4*)(beta  + j0);
  float xn[4];
  xn[0] = (v.x-mu)*rstd*g.x + b.x;
  xn[1] = (v.y-mu)*rstd*g.y + b.y;
  xn[2] = (v.z-mu)*rstd*g.z + b.z;
  xn[3] = (v.w-mu)*rstd*g.w + b.w;
  bf16x4 ov; ov[0]=(bf16_t)xn[0]; ov[1]=(bf16_t)xn[1]; ov[2]=(bf16_t)xn[2]; ov[3]=(bf16_t)xn[3];
  *(bf16x4*)(xnb + (size_t)t*DD + j0) = ov;

  float p[8] = {0,0,0,0,0,0,0,0};
  #pragma unroll
  for (int i = 0; i < 4; i++) {
    const float4 a0 = *(const float4*)(gw + (size_t)(j0+i)*EE);
    const float4 a1 = *(const float4*)(gw + (size_t)(j0+i)*EE + 4);
    const float xv = xn[i];
    p[0]+=xv*a0.x; p[1]+=xv*a0.y; p[2]+=xv*a0.z; p[3]+=xv*a0.w;
    p[4]+=xv*a1.x; p[5]+=xv*a1.y; p[6]+=xv*a1.z; p[7]+=xv*a1.w;
  }
  #pragma unroll
  for (int off = 32; off; off >>= 1) {
    #pragma unroll
    for (int e = 0; e < 8; e++) p[e] += __shfl_down(p[e], off);
  }
  __shared__ float pr[32];
  if (lid == 0) {
    #pragma unroll
    for (int e = 0; e < 8; e++) pr[wid*8 + e] = p[e];
  }
  __syncthreads();
  if (tid == 0) {
    float l[8];
    #pragma unroll
    for (int e = 0; e < 8; e++) l[e] = pr[e] + pr[8+e] + pr[16+e] + pr[24+e] + gb[e];
    int i1 = 0; float m1 = l[0];
    #pragma unroll
    for (int e = 1; e < 8; e++) if (l[e] > m1) { m1 = l[e]; i1 = e; }
    int i2 = 0; float m2 = -1e30f;
    #pragma unroll
    for (int e = 0; e < 8; e++) if (e != i1 && l[e] > m2) { m2 = l[e]; i2 = e; }
    const float wa = 1.0f/(1.0f + expf(m2 - m1));  // softmax over top-2
    ids[t] = make_int2(i1, i2);
    wts[t] = make_float2(wa, 1.0f - wa);
  }
}

// Deterministic slot assignment (ballot-scan), 128-aligned prefix offsets,
// and the compact active-tile table. No atomics, one launch.
__global__ __launch_bounds__(256)
void route_kernel(const int2* __restrict__ ids, int* __restrict__ slotA,
                  int* __restrict__ slotB, int* __restrict__ cnt,
                  int* __restrict__ off, int* __restrict__ tileE,
                  int* __restrict__ tileR, int* __restrict__ ntp)
{
  const int tid = threadIdx.x;
  const int wid = tid >> 6, lid = tid & 63;
  __shared__ int wsum[EE][4];
  __shared__ int base[EE];
  if (tid < EE) base[tid] = 0;
  __syncthreads();
  const unsigned long long lt = (1ull << lid) - 1ull;
  for (int c0 = 0; c0 < NTOK; c0 += 256) {
    const int t = c0 + tid;
    const int2 id = ids[t];
    int pA = 0, pB = 0;
    #pragma unroll
    for (int e = 0; e < EE; e++) {
      const bool fA = (id.x == e), fB = (id.y == e);
      const unsigned long long mA = __ballot(fA);
      const unsigned long long mB = __ballot(fB);
      const int cA = __popcll(mA);
      if (lid == 0) wsum[e][wid] = cA + __popcll(mB);
      if (fA) pA = __popcll(mA & lt);
      if (fB) pB = cA + __popcll(mB & lt);
    }
    __syncthreads();
    int wbA = base[id.x], wbB = base[id.y];
    for (int w = 0; w < wid; w++) { wbA += wsum[id.x][w]; wbB += wsum[id.y][w]; }
    slotA[t] = wbA + pA;
    slotB[t] = wbB + pB;
    __syncthreads();
    if (tid < EE) base[tid] += wsum[tid][0]+wsum[tid][1]+wsum[tid][2]+wsum[tid][3];
    __syncthreads();
  }
  if (tid == 0) {
    int a = 0, nt = 0;
    for (int e = 0; e < EE; e++) {
      cnt[e] = base[e]; off[e] = a;
      for (int r2 = 0; r2 < base[e]; r2 += 128) { tileE[nt] = e; tileR[nt] = r2; nt++; }
      a += (base[e] + 127) & ~127;
    }
    ntp[0] = nt;
  }
}

// tokOf[gathered_row] = token; block 0 zeroes pad rows (disjoint addresses).
__global__ __launch_bounds__(256)
void fill_tok_kernel(const int2* __restrict__ ids, const int* __restrict__ slotA,
                     const int* __restrict__ slotB, const int* __restrict__ off,
                     const int* __restrict__ cnt, int* __restrict__ tokOf){
  const int t = blockIdx.x*256 + threadIdx.x;
  const int2 id = ids[t];
  tokOf[off[id.x] + slotA[t]] = t;
  tokOf[off[id.y] + slotB[t]] = t;
  if (blockIdx.x == 0) {
    for (int e = 0; e < EE; e++) {
      const int c = cnt[e], o = off[e], al = (c + 127) & ~127;
      for (int p = c + threadIdx.x; p < al; p += 256) tokOf[o + p] = 0;
    }
  }
}

// Xa[t] = bf16(w1*Yg[loc1] + w2*Yg[loc2])
__global__ __launch_bounds__(256)
void combine_kernel(const bf16_t* __restrict__ Yg, const int2* __restrict__ ids,
                    const int* __restrict__ slotA, const int* __restrict__ slotB,
                    const int* __restrict__ off, const float2* __restrict__ wts,
                    bf16_t* __restrict__ Xa){
  const int t = blockIdx.x, j = threadIdx.x*4;
  const int2 id = ids[t];
  const float2 w = wts[t];
  const bf16x4 a = *(const bf16x4*)(Yg + (size_t)(off[id.x] + slotA[t])*DD + j);
  const bf16x4 b = *(const bf16x4*)(Yg + (size_t)(off[id.y] + slotB[t])*DD + j);
  bf16x4 o;
  #pragma unroll
  for (int i = 0; i < 4; i++) o[i] = (bf16_t)(w.x*(float)a[i] + w.y*(float)b[i]);
  *(bf16x4*)(Xa + (size_t)t*DD + j) = o;
}

__global__ __launch_bounds__(256)
void mix_kernel(const float* __restrict__ x, const bf16_t* __restrict__ abel,
                const bf16_t* __restrict__ rot, const float* __restrict__ gcw,
                const float* __restrict__ gcb, float* __restrict__ out)
{
  const int t = blockIdx.x, tid = threadIdx.x, j0 = tid*4;
  const int wid = tid >> 6, lid = tid & 63;
  const bf16x4 ab = *(const bf16x4*)(abel + (size_t)t*DD + j0);
  const bf16x4 rb = *(const bf16x4*)(rot  + (size_t)t*DD + j0);
  const float4 ga = *(const float4*)(gcw + j0);
  const float4 gr = *(const float4*)(gcw + DD + j0);
  const float a0 = (float)ab[0], a1 = (float)ab[1], a2 = (float)ab[2], a3 = (float)ab[3];
  const float r0 = (float)rb[0], r1 = (float)rb[1], r2 = (float)rb[2], r3 = (float)rb[3];
  float p = a0*ga.x + a1*ga.y + a2*ga.z + a3*ga.w
          + r0*gr.x + r1*gr.y + r2*gr.z + r3*gr.w;
  #pragma unroll
  for (int off = 32; off; off >>= 1) p += __shfl_down(p, off);
  __shared__ float red[4];
  __shared__ float gsh;
  if (lid == 0) red[wid] = p;
  __syncthreads();
  if (tid == 0) {
    const float P = red[0] + red[1] + red[2] + red[3] + gcb[0];
    gsh = 1.0f/(1.0f + expf(-P));
  }
  __syncthreads();
  const float gate = gsh, g1 = 1.0f - gate;
  const float4 xv = *(const float4*)(x + (size_t)t*DD + j0);
  float4 o;
  o.x = xv.x + a0*g1 + r0*gate;
  o.y = xv.y + a1*g1 + r1*gate;
  o.z = xv.z + a2*g1 + r2*gate;
  o.w = xv.w + a3*g1 + r3*gate;
  *(float4*)(out + (size_t)t*DD + j0) = o;
}

extern "C" void kernel_launch(void* const* d_in, const int* in_sizes, int n_in,
                              void* d_out, int out_size, void* d_ws, size_t ws_size,
                              hipStream_t stream)
{
  (void)in_sizes; (void)n_in; (void)out_size; (void)ws_size;
  const float* x      = (const float*)d_in[0];
  const float* ln_g   = (const float*)d_in[1];
  const float* ln_b   = (const float*)d_in[2];
  const float* abel_w = (const float*)d_in[3];
  const float* abel_b = (const float*)d_in[4];
  const float* gate_w = (const float*)d_in[5];
  const float* gate_b = (const float*)d_in[6];
  const float* ew1    = (const float*)d_in[7];
  const float* eb1    = (const float*)d_in[8];
  const float* ew2    = (const float*)d_in[9];
  const float* eb2    = (const float*)d_in[10];
  const float* gens   = (const float*)d_in[11];
  const float* gc_w   = (const float*)d_in[12];
  const float* gc_b   = (const float*)d_in[13];
  float* out = (float*)d_out;

  char* wsp = (char*)d_ws;
  auto alloc = [&](size_t bytes) -> char* {
    char* p = wsp; wsp += (bytes + 255) & ~(size_t)255; return p;
  };
  const size_t MB = 1u<<20;
  bf16_t* xnb   = (bf16_t*)alloc((size_t)NTOK*DD*2);
  int2*   ids   = (int2*)  alloc((size_t)NTOK*8);
  float2* wts   = (float2*)alloc((size_t)NTOK*8);
  int*    slotA = (int*)   alloc((size_t)NTOK*4);
  int*    slotB = (int*)   alloc((size_t)NTOK*4);
  int*    cnt   = (int*)   alloc(64);
  int*    off   = (int*)   alloc(64);
  int*    tileE = (int*)   alloc(MAXT*4);
  int*    tileR = (int*)   alloc(MAXT*4);
  int*    ntp   = (int*)   alloc(64);
  int*    tokOf = (int*)   alloc((size_t)CAPR*4);
  bf16_t* abel_wT = (bf16_t*)alloc((size_t)DD*DD*2);
  char*   UN      = alloc(64*MB);            // ew1T(32MB)+ew2T(32MB); PS temps overlay
  bf16_t* ew1T  = (bf16_t*)UN;
  bf16_t* ew2T  = (bf16_t*)(UN + 32*MB);
  bf16_t* Hn    = (bf16_t*)alloc((size_t)3*DD*DD*2);
  bf16_t* abelo = (bf16_t*)alloc((size_t)NTOK*DD*2);
  bf16_t* Yg    = (bf16_t*)alloc((size_t)CAPR*DD*2);   // down output (gathered)
  bf16_t* Hg    = (bf16_t*)alloc((size_t)CAPR*DD2*2);  // up output; also rotB
  bf16_t* Xa    = (bf16_t*)alloc((size_t)NTOK*DD*2);
  bf16_t* rotB  = (bf16_t*)Hg;                          // rot output (bf16), aliases Hg
  // PS temps over UN (dead after up/down GEMMs)
  bf16_t* H2  = (bf16_t*)(UN + 0*MB);
  bf16_t* H3  = (bf16_t*)(UN + 6*MB);
  bf16_t* Vb  = (bf16_t*)(UN + 12*MB);
  bf16_t* Wtb = (bf16_t*)(UN + 18*MB);
  bf16_t* Ut  = (bf16_t*)(UN + 24*MB);
  bf16_t* Tb  = (bf16_t*)(UN + 30*MB);
  bf16_t* Pb  = (bf16_t*)(UN + 34*MB);
  bf16_t* Rt  = (bf16_t*)(UN + 36*MB);
  const long D2 = (long)DD*DD;

  auto gflat = [](int gx, int gy, int gz) {
    const int nwg = gx*gy*gz; return 8 * ((nwg + 7) / 8);
  };

  // one launch: abel_wT + ew1T + ew2T transposes + Hn = -gens (bf16)
  prep_kernel<<<dim3(11520,1,1), 256, 0, stream>>>(abel_w, abel_wT, ew1, ew1T,
                                                   ew2, ew2T, gens, Hn);

  ln_gate_kernel<<<dim3(NTOK,1,1), 256, 0, stream>>>(x, ln_g, ln_b, gate_w, gate_b,
                                                     xnb, ids, wts);
  route_kernel<<<dim3(1,1,1), 256, 0, stream>>>(ids, slotA, slotB, cnt, off,
                                                tileE, tileR, ntp);
  fill_tok_kernel<<<dim3(NTOK/256,1,1), 256, 0, stream>>>(ids, slotA, slotB, off, cnt, tokOf);

  // sparse MoE: 128x128 3-deep (measured optimum); fused gather via tokOf
  gemm_bt<128,128,EPI_GELU_BF16,true><<<dim3((DD2/128)*MAXT,1,1), 256, 0, stream>>>(
      xnb, ew1T, DD2, DD, DD2/128, MAXT, 1, 0, (long)DD2*DD, 0,
      tileE, tileR, ntp, off, tokOf, eb1, DD2, 1.0f, nullptr, nullptr, Hg);
  gemm_bt<128,128,EPI_BIAS_BF16,true><<<dim3((DD/128)*MAXT,1,1), 256, 0, stream>>>(
      Hg, ew2T, DD, DD2, DD/128, MAXT, 1, 0, (long)DD*DD2, 0,
      tileE, tileR, ntp, off, nullptr, eb2, DD, 1.0f, nullptr, nullptr, Yg);
  combine_kernel<<<dim3(NTOK,1,1), 256, 0, stream>>>(Yg, ids, slotA, slotB, off, wts, Xa);

  // abel branch: 128x64 -> 512 blocks = 2 blk/CU
  gemm_bt<128,64,EPI_GELU_BF16,false><<<dim3(gflat(16,32,1),1,1), 256, 0, stream>>>(
      xnb, abel_wT, DD, DD, 16, 32, 1, 0, 0, 0, nullptr, nullptr, nullptr, nullptr,
      nullptr, abel_b, 0, 1.0f, nullptr, nullptr, abelo);

  // Degree-5 Paterson-Stockmeyer expm(H), H = -G (skew). 64x64 tiles.
  gemm_bt<64,64,EPI_SCALE_BF16,false><<<dim3(gflat(16,16,3),1,1), 256, 0, stream>>>(
      Hn, Hn, DD, DD, 16, 16, 3, D2, D2, D2, nullptr, nullptr, nullptr, nullptr,
      nullptr, nullptr, 0, -1.0f, nullptr, nullptr, H2);
  gemm_bt<64,64,EPI_SCALE_BF16,false><<<dim3(gflat(16,16,3),1,1), 256, 0, stream>>>(
      H2, Hn, DD, DD, 16, 16, 3, D2, D2, D2, nullptr, nullptr, nullptr, nullptr,
      nullptr, nullptr, 0, -1.0f, nullptr, nullptr, H3);
  vw_kernel<<<dim3(3*DD*DD/1024,1,1), 256, 0, stream>>>(Hn, H2, Vb, Wtb);
  gemm_bt<64,64,EPI_ADDV_BF16,false><<<dim3(gflat(16,16,3),1,1), 256, 0, stream>>>(
      H3, Wtb, DD, DD, 16, 16, 3, D2, D2, D2, nullptr, nullptr, nullptr, nullptr,
      nullptr, nullptr, 0, 1.0f, Vb, nullptr, Ut);
  // Rt = Ut2 @ Ut1 @ Ut0
  tb16_kernel<<<dim3(32,32,2), dim3(32,8,1), 0, stream>>>(Ut, Tb);
  gemm_bt<64,64,EPI_BF16,false><<<dim3(gflat(16,16,1),1,1), 256, 0, stream>>>(
      Ut + 2*D2, Tb, DD, DD, 16, 16, 1, 0, 0, 0, nullptr, nullptr, nullptr, nullptr,
      nullptr, nullptr, 0, 1.0f, nullptr, nullptr, Pb);
  gemm_bt<64,64,EPI_BF16,false><<<dim3(gflat(16,16,1),1,1), 256, 0, stream>>>(
      Pb, Tb + D2, DD, DD, 16, 16, 1, 0, 0, 0, nullptr, nullptr, nullptr, nullptr,
      nullptr, nullptr, 0, 1.0f, nullptr, nullptr, Rt);
  // rot = Xa @ Rt^T (bf16 output: halves rot write + mix read traffic)
  gemm_bt<128,64,EPI_BF16,false><<<dim3(gflat(16,32,1),1,1), 256, 0, stream>>>(
      Xa, Rt, DD, DD, 16, 32, 1, 0, 0, 0, nullptr, nullptr, nullptr, nullptr,
      nullptr, nullptr, 0, 1.0f, nullptr, nullptr, rotB);

  mix_kernel<<<dim3(NTOK,1,1), 256, 0, stream>>>(x, abelo, rotB, gc_w, gc_b, out);
}